// Round 1
// baseline (839.879 us; speedup 1.0000x reference)
//
#include <hip/hip_runtime.h>

// piSGC: 2-layer edge-weighted SGC on MI355X.
// Stages: deg scatter -> rsqrt -> conv1 (atomic scatter) -> conv2 -> fused linear+log_softmax.

#define ALPHA  0.05f
#define SCALE  0.475f   // (1 - ALPHA) / NUM_LAYERS, NUM_LAYERS = 2
#define FDIM   64
#define CDIM   40

// ---- Stage 1: deg[col[e]] += edge_attr[e] ----
__global__ void deg_kernel(const float* __restrict__ ea,
                           const int* __restrict__ col,
                           float* __restrict__ deg, int E) {
    int stride = gridDim.x * blockDim.x;
    for (int e = blockIdx.x * blockDim.x + threadIdx.x; e < E; e += stride) {
        unsafeAtomicAdd(&deg[col[e]], ea[e]);
    }
}

// ---- Stage 2: dis[n] = deg>0 ? rsqrt(max(deg,1e-12)) : 0  (in-place) ----
__global__ void dis_kernel(float* __restrict__ deg, int N) {
    int stride = gridDim.x * blockDim.x;
    for (int n = blockIdx.x * blockDim.x + threadIdx.x; n < N; n += stride) {
        float d = deg[n];
        deg[n] = (d > 0.0f) ? rsqrtf(fmaxf(d, 1e-12f)) : 0.0f;
    }
}

// ---- Stage 3/4: hout[col] += (dis[row]*ea*dis[col]) * hin[row]  (wave per edge) ----
__global__ void conv_kernel(const float* __restrict__ hin,
                            const float* __restrict__ ea,
                            const int* __restrict__ row,
                            const int* __restrict__ col,
                            const float* __restrict__ dis,
                            float* __restrict__ hout, int E) {
    int lane   = threadIdx.x & 63;
    int wave   = (blockIdx.x * blockDim.x + threadIdx.x) >> 6;
    int nwaves = (gridDim.x * blockDim.x) >> 6;
    for (int e = wave; e < E; e += nwaves) {
        int r = row[e];
        int c = col[e];
        float w = dis[r] * ea[e] * dis[c];
        float v = w * hin[r * FDIM + lane];
        unsafeAtomicAdd(&hout[c * FDIM + lane], v);
    }
}

// ---- Stage 5: out = log_softmax( (ALPHA*x + SCALE*(h1+h2)) @ W + b ) ----
__global__ __launch_bounds__(256) void final_kernel(
        const float* __restrict__ x,
        const float* __restrict__ h1,
        const float* __restrict__ h2,
        const float* __restrict__ W,   // [64][40]
        const float* __restrict__ b,   // [40]
        float* __restrict__ out, int N) {
    __shared__ float sW[FDIM * CDIM];
    __shared__ float sb[CDIM];
    for (int i = threadIdx.x; i < FDIM * CDIM; i += blockDim.x) sW[i] = W[i];
    if (threadIdx.x < CDIM) sb[threadIdx.x] = b[threadIdx.x];
    __syncthreads();

    int n = blockIdx.x * blockDim.x + threadIdx.x;
    if (n >= N) return;

    float logits[CDIM];
    #pragma unroll
    for (int c = 0; c < CDIM; ++c) logits[c] = sb[c];

    const float* xr  = x  + (size_t)n * FDIM;
    const float* h1r = h1 + (size_t)n * FDIM;
    const float* h2r = h2 + (size_t)n * FDIM;

    #pragma unroll 8
    for (int k = 0; k < FDIM; ++k) {
        float v = ALPHA * xr[k] + SCALE * (h1r[k] + h2r[k]);
        const float* wk = &sW[k * CDIM];
        #pragma unroll
        for (int c = 0; c < CDIM; ++c)
            logits[c] = fmaf(v, wk[c], logits[c]);
    }

    float m = logits[0];
    #pragma unroll
    for (int c = 1; c < CDIM; ++c) m = fmaxf(m, logits[c]);
    float s = 0.0f;
    #pragma unroll
    for (int c = 0; c < CDIM; ++c) s += expf(logits[c] - m);
    float lse = m + logf(s);

    float* o = out + (size_t)n * CDIM;
    #pragma unroll
    for (int c = 0; c < CDIM; ++c) o[c] = logits[c] - lse;
}

extern "C" void kernel_launch(void* const* d_in, const int* in_sizes, int n_in,
                              void* d_out, int out_size, void* d_ws, size_t ws_size,
                              hipStream_t stream) {
    const float* x  = (const float*)d_in[0];   // [N,64]
    const float* ea = (const float*)d_in[1];   // [E]
    const float* W  = (const float*)d_in[2];   // [64,40]
    const float* b  = (const float*)d_in[3];   // [40]
    const int*   ei = (const int*)d_in[4];     // [2,E] flattened: row then col

    const int N = in_sizes[0] / FDIM;
    const int E = in_sizes[1];
    const int* row = ei;
    const int* col = ei + E;

    float* ws  = (float*)d_ws;
    float* deg = ws;                       // N floats; becomes dis in-place
    float* h1  = ws + 131072;              // N*64 floats
    float* h2  = h1 + (size_t)N * FDIM;    // N*64 floats

    size_t zero_bytes = (131072 + 2 * (size_t)N * FDIM) * sizeof(float);
    hipMemsetAsync(d_ws, 0, zero_bytes, stream);

    deg_kernel<<<2048, 256, 0, stream>>>(ea, col, deg, E);
    dis_kernel<<<(N + 255) / 256, 256, 0, stream>>>(deg, N);
    conv_kernel<<<4096, 256, 0, stream>>>(x,  ea, row, col, deg, h1, E);
    conv_kernel<<<4096, 256, 0, stream>>>(h1, ea, row, col, deg, h2, E);
    final_kernel<<<(N + 255) / 256, 256, 0, stream>>>(x, h1, h2, W, b, (float*)d_out, N);
}

// Round 2
// 681.218 us; speedup vs baseline: 1.2329x; 1.2329x over previous
//
#include <hip/hip_runtime.h>

// piSGC: 2-layer edge-weighted SGC on MI355X.
// R2: algebraic reorder — apply linear layer FIRST (y = x@W, N x 40), then
// propagate 40-dim vectors through the graph twice. Cuts edge gather/scatter
// payload by 64->40 and removes the matmul from the epilogue.

#define ALPHA  0.05f
#define SCALE  0.475f   // (1 - ALPHA) / NUM_LAYERS, NUM_LAYERS = 2
#define FDIM   64
#define CDIM   40

// ---- y = x @ W  (one thread per node; W staged in LDS) ----
__global__ __launch_bounds__(256) void lin_kernel(
        const float* __restrict__ x,
        const float* __restrict__ W,   // [64][40]
        float* __restrict__ y, int N) {
    __shared__ float sW[FDIM * CDIM];
    for (int i = threadIdx.x; i < FDIM * CDIM; i += blockDim.x) sW[i] = W[i];
    __syncthreads();

    int n = blockIdx.x * blockDim.x + threadIdx.x;
    if (n >= N) return;

    float acc[CDIM];
    #pragma unroll
    for (int c = 0; c < CDIM; ++c) acc[c] = 0.0f;

    const float4* xr = (const float4*)(x + (size_t)n * FDIM);
    #pragma unroll
    for (int k4 = 0; k4 < FDIM / 4; ++k4) {
        float4 v = xr[k4];
        const float* wk = &sW[k4 * 4 * CDIM];
        #pragma unroll
        for (int c = 0; c < CDIM; ++c) acc[c] = fmaf(v.x, wk[c], acc[c]);
        wk += CDIM;
        #pragma unroll
        for (int c = 0; c < CDIM; ++c) acc[c] = fmaf(v.y, wk[c], acc[c]);
        wk += CDIM;
        #pragma unroll
        for (int c = 0; c < CDIM; ++c) acc[c] = fmaf(v.z, wk[c], acc[c]);
        wk += CDIM;
        #pragma unroll
        for (int c = 0; c < CDIM; ++c) acc[c] = fmaf(v.w, wk[c], acc[c]);
    }
    float* yr = y + (size_t)n * CDIM;
    #pragma unroll
    for (int c = 0; c < CDIM; ++c) yr[c] = acc[c];
}

// ---- deg[col[e]] += edge_attr[e] ----
__global__ void deg_kernel(const float* __restrict__ ea,
                           const int* __restrict__ col,
                           float* __restrict__ deg, int E) {
    int stride = gridDim.x * blockDim.x;
    for (int e = blockIdx.x * blockDim.x + threadIdx.x; e < E; e += stride) {
        unsafeAtomicAdd(&deg[col[e]], ea[e]);
    }
}

// ---- dis[n] = deg>0 ? rsqrt(max(deg,1e-12)) : 0  (in-place) ----
__global__ void dis_kernel(float* __restrict__ deg, int N) {
    int stride = gridDim.x * blockDim.x;
    for (int n = blockIdx.x * blockDim.x + threadIdx.x; n < N; n += stride) {
        float d = deg[n];
        deg[n] = (d > 0.0f) ? rsqrtf(fmaxf(d, 1e-12f)) : 0.0f;
    }
}

// ---- gout[col] += (dis[row]*ea*dis[col]) * gin[row], 40 feats/edge ----
// thread t -> edge e = t/40, feature f = t%40
__global__ void conv_kernel(const float* __restrict__ gin,
                            const float* __restrict__ ea,
                            const int* __restrict__ row,
                            const int* __restrict__ col,
                            const float* __restrict__ dis,
                            float* __restrict__ gout, int E) {
    int total  = E * CDIM;
    int stride = gridDim.x * blockDim.x;
    for (int t = blockIdx.x * blockDim.x + threadIdx.x; t < total; t += stride) {
        unsigned ut = (unsigned)t;
        unsigned e  = ut / CDIM;         // compiler -> magic multiply
        unsigned f  = ut - e * CDIM;
        int r = row[e];
        int c = col[e];
        float w = dis[r] * ea[e] * dis[c];
        float v = w * gin[(size_t)r * CDIM + f];
        unsafeAtomicAdd(&gout[(size_t)c * CDIM + f], v);
    }
}

// ---- out = log_softmax( 0.05*y + 0.475*(g1+g2) + b ) ----
__global__ __launch_bounds__(256) void final_kernel(
        const float* __restrict__ y,
        const float* __restrict__ g1,
        const float* __restrict__ g2,
        const float* __restrict__ b,   // [40]
        float* __restrict__ out, int N) {
    __shared__ float sb[CDIM];
    if (threadIdx.x < CDIM) sb[threadIdx.x] = b[threadIdx.x];
    __syncthreads();

    int n = blockIdx.x * blockDim.x + threadIdx.x;
    if (n >= N) return;

    const float* yr  = y  + (size_t)n * CDIM;
    const float* g1r = g1 + (size_t)n * CDIM;
    const float* g2r = g2 + (size_t)n * CDIM;

    float logits[CDIM];
    #pragma unroll
    for (int c = 0; c < CDIM; ++c)
        logits[c] = fmaf(ALPHA, yr[c], fmaf(SCALE, g1r[c] + g2r[c], sb[c]));

    float m = logits[0];
    #pragma unroll
    for (int c = 1; c < CDIM; ++c) m = fmaxf(m, logits[c]);
    float s = 0.0f;
    #pragma unroll
    for (int c = 0; c < CDIM; ++c) s += expf(logits[c] - m);
    float lse = m + logf(s);

    float* o = out + (size_t)n * CDIM;
    #pragma unroll
    for (int c = 0; c < CDIM; ++c) o[c] = logits[c] - lse;
}

extern "C" void kernel_launch(void* const* d_in, const int* in_sizes, int n_in,
                              void* d_out, int out_size, void* d_ws, size_t ws_size,
                              hipStream_t stream) {
    const float* x  = (const float*)d_in[0];   // [N,64]
    const float* ea = (const float*)d_in[1];   // [E]
    const float* W  = (const float*)d_in[2];   // [64,40]
    const float* b  = (const float*)d_in[3];   // [40]
    const int*   ei = (const int*)d_in[4];     // [2,E]: row then col

    const int N = in_sizes[0] / FDIM;
    const int E = in_sizes[1];
    const int* row = ei;
    const int* col = ei + E;

    float* ws  = (float*)d_ws;
    float* deg = ws;                            // N floats (becomes dis)
    float* g1  = ws + 131072;                   // N*40
    float* g2  = g1 + (size_t)N * CDIM;         // N*40
    float* y   = g2 + (size_t)N * CDIM;         // N*40

    // zero deg + g1 + g2 (y is fully overwritten by lin_kernel)
    size_t zero_bytes = (131072 + 2 * (size_t)N * CDIM) * sizeof(float);
    hipMemsetAsync(d_ws, 0, zero_bytes, stream);

    lin_kernel<<<(N + 255) / 256, 256, 0, stream>>>(x, W, y, N);
    deg_kernel<<<2048, 256, 0, stream>>>(ea, col, deg, E);
    dis_kernel<<<(N + 255) / 256, 256, 0, stream>>>(deg, N);
    conv_kernel<<<8192, 256, 0, stream>>>(y,  ea, row, col, deg, g1, E);
    conv_kernel<<<8192, 256, 0, stream>>>(g1, ea, row, col, deg, g2, E);
    final_kernel<<<(N + 255) / 256, 256, 0, stream>>>(y, g1, g2, b, (float*)d_out, N);
}

// Round 3
// 462.549 us; speedup vs baseline: 1.8158x; 1.4727x over previous
//
#include <hip/hip_runtime.h>
#include <math.h>

// piSGC R3: CSR-gather formulation. Build CSR (grouped by target col) on
// device each call, fold norm into edge weight, then both conv layers are
// pure gathers (wave per node, lanes 0-39 = features) with NO fp32 scatter
// atomics. conv2 fused with log-softmax epilogue.

#define ALPHA  0.05f
#define SCALE  0.475f   // (1 - ALPHA) / NUM_LAYERS
#define FDIM   64
#define CDIM   40
#define NPAD   131072

// ---- y = x @ W ----
__global__ __launch_bounds__(256) void lin_kernel(
        const float* __restrict__ x, const float* __restrict__ W,
        float* __restrict__ y, int N) {
    __shared__ float sW[FDIM * CDIM];
    for (int i = threadIdx.x; i < FDIM * CDIM; i += blockDim.x) sW[i] = W[i];
    __syncthreads();
    int n = blockIdx.x * blockDim.x + threadIdx.x;
    if (n >= N) return;
    float acc[CDIM];
    #pragma unroll
    for (int c = 0; c < CDIM; ++c) acc[c] = 0.0f;
    const float4* xr = (const float4*)(x + (size_t)n * FDIM);
    #pragma unroll
    for (int k4 = 0; k4 < FDIM / 4; ++k4) {
        float4 v = xr[k4];
        const float* wk = &sW[k4 * 4 * CDIM];
        #pragma unroll
        for (int c = 0; c < CDIM; ++c) acc[c] = fmaf(v.x, wk[c], acc[c]);
        #pragma unroll
        for (int c = 0; c < CDIM; ++c) acc[c] = fmaf(v.y, wk[CDIM + c], acc[c]);
        #pragma unroll
        for (int c = 0; c < CDIM; ++c) acc[c] = fmaf(v.z, wk[2 * CDIM + c], acc[c]);
        #pragma unroll
        for (int c = 0; c < CDIM; ++c) acc[c] = fmaf(v.w, wk[3 * CDIM + c], acc[c]);
    }
    float* yr = y + (size_t)n * CDIM;
    #pragma unroll
    for (int c = 0; c < CDIM; ++c) yr[c] = acc[c];
}

// ---- weighted degree + in-degree count ----
__global__ void hist_kernel(const float* __restrict__ ea,
                            const int* __restrict__ col,
                            float* __restrict__ deg, int* __restrict__ cnt, int E) {
    int stride = gridDim.x * blockDim.x;
    for (int e = blockIdx.x * blockDim.x + threadIdx.x; e < E; e += stride) {
        int c = col[e];
        unsafeAtomicAdd(&deg[c], ea[e]);
        atomicAdd(&cnt[c], 1);
    }
}

// ---- dis = deg>0 ? rsqrt(max(deg,1e-12)) : 0  (in-place) ----
__global__ void dis_kernel(float* __restrict__ deg, int N) {
    int stride = gridDim.x * blockDim.x;
    for (int n = blockIdx.x * blockDim.x + threadIdx.x; n < N; n += stride) {
        float d = deg[n];
        deg[n] = (d > 0.0f) ? rsqrtf(fmaxf(d, 1e-12f)) : 0.0f;
    }
}

// ---- scan pass 1: per-256-chunk inclusive scan of cnt -> start, chunk sums ----
__global__ __launch_bounds__(256) void scan_p1(const int* __restrict__ cnt,
                                               int* __restrict__ start,
                                               int* __restrict__ bsums, int N) {
    __shared__ int s[256];
    int tid = threadIdx.x;
    int i = blockIdx.x * 256 + tid;
    int v = (i < N) ? cnt[i] : 0;
    s[tid] = v;
    __syncthreads();
    for (int off = 1; off < 256; off <<= 1) {
        int t = (tid >= off) ? s[tid - off] : 0;
        __syncthreads();
        s[tid] += t;
        __syncthreads();
    }
    if (i < N) start[i] = s[tid];
    if (tid == 255) bsums[blockIdx.x] = s[255];
}

// ---- scan pass 2: exclusive scan of chunk sums (single block, chunked) ----
__global__ __launch_bounds__(1024) void scan_p2(int* __restrict__ bsums, int NB) {
    __shared__ int s[1024];
    int tid = threadIdx.x;
    int carry = 0;
    for (int base = 0; base < NB; base += 1024) {
        int i = base + tid;
        int v = (i < NB) ? bsums[i] : 0;
        s[tid] = v;
        __syncthreads();
        for (int off = 1; off < 1024; off <<= 1) {
            int t = (tid >= off) ? s[tid - off] : 0;
            __syncthreads();
            s[tid] += t;
            __syncthreads();
        }
        if (i < NB) bsums[i] = carry + s[tid] - v;   // exclusive + carry
        int tot = s[1023];
        __syncthreads();
        carry += tot;
    }
}

// ---- scan pass 3: start[i] = exclusive global offset; start[N] = E ----
__global__ __launch_bounds__(256) void scan_p3(int* __restrict__ start,
                                               const int* __restrict__ cnt,
                                               const int* __restrict__ bsums,
                                               int N, int E) {
    int i = blockIdx.x * 256 + threadIdx.x;
    if (i < N) start[i] += bsums[blockIdx.x] - cnt[i];
    if (i == 0) start[N] = E;
}

// ---- fill CSR: slot via per-node counter; weight = dis[r]*ea*dis[c] ----
__global__ void fill_kernel(const int* __restrict__ row, const int* __restrict__ col,
                            const float* __restrict__ ea, const float* __restrict__ dis,
                            const int* __restrict__ start, int* __restrict__ fillp,
                            int* __restrict__ csr_s, float* __restrict__ csr_w, int E) {
    int stride = gridDim.x * blockDim.x;
    for (int e = blockIdx.x * blockDim.x + threadIdx.x; e < E; e += stride) {
        int c = col[e];
        int r = row[e];
        int p = start[c] + atomicAdd(&fillp[c], 1);
        csr_s[p] = r;
        csr_w[p] = dis[r] * ea[e] * dis[c];
    }
}

// ---- gather conv: gout[n,f] = sum_j w_j * gin[src_j, f]  (wave per node) ----
__global__ __launch_bounds__(256) void spmv_kernel(
        const float* __restrict__ gin, const int* __restrict__ start,
        const int* __restrict__ csr_s, const float* __restrict__ csr_w,
        float* __restrict__ gout, int N) {
    int node = (blockIdx.x * blockDim.x + threadIdx.x) >> 6;
    int lane = threadIdx.x & 63;
    if (node >= N) return;
    int e0 = start[node], e1 = start[node + 1];
    float acc = 0.0f;
    int j = e0;
    for (; j + 1 < e1; j += 2) {
        int r0 = csr_s[j], r1 = csr_s[j + 1];
        float w0 = csr_w[j], w1 = csr_w[j + 1];
        if (lane < CDIM) {
            acc = fmaf(w0, gin[(size_t)r0 * CDIM + lane], acc);
            acc = fmaf(w1, gin[(size_t)r1 * CDIM + lane], acc);
        }
    }
    if (j < e1) {
        int r = csr_s[j]; float w = csr_w[j];
        if (lane < CDIM) acc = fmaf(w, gin[(size_t)r * CDIM + lane], acc);
    }
    if (lane < CDIM) gout[(size_t)node * CDIM + lane] = acc;
}

// ---- conv2 + epilogue: logits = 0.05y + 0.475(g1+g2) + b; log_softmax ----
__global__ __launch_bounds__(256) void spmv_final_kernel(
        const float* __restrict__ g1, const float* __restrict__ y,
        const float* __restrict__ bias, const int* __restrict__ start,
        const int* __restrict__ csr_s, const float* __restrict__ csr_w,
        float* __restrict__ out, int N) {
    int node = (blockIdx.x * blockDim.x + threadIdx.x) >> 6;
    int lane = threadIdx.x & 63;
    if (node >= N) return;
    int e0 = start[node], e1 = start[node + 1];
    float acc = 0.0f;   // g2 row
    int j = e0;
    for (; j + 1 < e1; j += 2) {
        int r0 = csr_s[j], r1 = csr_s[j + 1];
        float w0 = csr_w[j], w1 = csr_w[j + 1];
        if (lane < CDIM) {
            acc = fmaf(w0, g1[(size_t)r0 * CDIM + lane], acc);
            acc = fmaf(w1, g1[(size_t)r1 * CDIM + lane], acc);
        }
    }
    if (j < e1) {
        int r = csr_s[j]; float w = csr_w[j];
        if (lane < CDIM) acc = fmaf(w, g1[(size_t)r * CDIM + lane], acc);
    }
    float logit = 0.0f;
    if (lane < CDIM) {
        float yv  = y[(size_t)node * CDIM + lane];
        float g1v = g1[(size_t)node * CDIM + lane];
        logit = fmaf(ALPHA, yv, fmaf(SCALE, g1v + acc, bias[lane]));
    }
    float ml = (lane < CDIM) ? logit : -INFINITY;
    #pragma unroll
    for (int off = 32; off; off >>= 1) ml = fmaxf(ml, __shfl_xor(ml, off));
    float ex = (lane < CDIM) ? expf(logit - ml) : 0.0f;
    #pragma unroll
    for (int off = 32; off; off >>= 1) ex += __shfl_xor(ex, off);
    float lse = ml + logf(ex);
    if (lane < CDIM) out[(size_t)node * CDIM + lane] = logit - lse;
}

extern "C" void kernel_launch(void* const* d_in, const int* in_sizes, int n_in,
                              void* d_out, int out_size, void* d_ws, size_t ws_size,
                              hipStream_t stream) {
    const float* x  = (const float*)d_in[0];   // [N,64]
    const float* ea = (const float*)d_in[1];   // [E]
    const float* W  = (const float*)d_in[2];   // [64,40]
    const float* b  = (const float*)d_in[3];   // [40]
    const int*   ei = (const int*)d_in[4];     // [2,E]: row then col

    const int N = in_sizes[0] / FDIM;
    const int E = in_sizes[1];
    const int* row = ei;
    const int* col = ei + E;
    const int NB = (N + 255) / 256;

    // workspace layout (all 4-byte elems)
    float* deg   = (float*)d_ws;                 // NPAD  (becomes dis)
    int*   cnt   = (int*)(deg + NPAD);           // NPAD
    int*   fillp = cnt + NPAD;                   // NPAD
    int*   start = fillp + NPAD;                 // N+1 (<= NPAD)
    int*   bsums = start + NPAD;                 // NB (<= 1024)
    float* csr_w = (float*)(bsums + 1024);       // E
    int*   csr_s = (int*)(csr_w + E);            // E
    float* y     = (float*)(csr_s + E);          // N*CDIM
    float* g1    = y + (size_t)N * CDIM;         // N*CDIM

    // zero deg + cnt + fillp (contiguous)
    hipMemsetAsync(d_ws, 0, (size_t)3 * NPAD * sizeof(float), stream);

    lin_kernel <<<(N + 255) / 256, 256, 0, stream>>>(x, W, y, N);
    hist_kernel<<<2048, 256, 0, stream>>>(ea, col, deg, cnt, E);
    dis_kernel <<<NB, 256, 0, stream>>>(deg, N);
    scan_p1    <<<NB, 256, 0, stream>>>(cnt, start, bsums, N);
    scan_p2    <<<1, 1024, 0, stream>>>(bsums, NB);
    scan_p3    <<<NB, 256, 0, stream>>>(start, cnt, bsums, N, E);
    fill_kernel<<<2048, 256, 0, stream>>>(row, col, ea, deg, start, fillp, csr_s, csr_w, E);

    int conv_blocks = (int)(((size_t)N * 64 + 255) / 256);
    spmv_kernel      <<<conv_blocks, 256, 0, stream>>>(y, start, csr_s, csr_w, g1, N);
    spmv_final_kernel<<<conv_blocks, 256, 0, stream>>>(g1, y, b, start, csr_s, csr_w,
                                                       (float*)d_out, N);
}

// Round 4
// 361.856 us; speedup vs baseline: 2.3210x; 1.2783x over previous
//
#include <hip/hip_runtime.h>
#include <math.h>

// piSGC R4: CSR-gather with minimal atomics.
//  - hist: 1 int atomic/edge, atomic return value IS the CSR slot
//  - fill: atomic-free, packed int2{src, ea_bits} CSR payload
//  - deg:  contiguous segment-sum over CSR (no float atomics)
//  - spmv: pure gather, dis folded at gather (src) and store (dst)
//  - conv2 fused with log-softmax epilogue

#define ALPHA  0.05f
#define SCALE  0.475f   // (1 - ALPHA) / NUM_LAYERS
#define FDIM   64
#define CDIM   40
#define NPAD   131072

// ---- hist: slot[e] = cnt[col[e]]++  ----
__global__ void hist_kernel(const int* __restrict__ col,
                            int* __restrict__ cnt,
                            int* __restrict__ slot, int E) {
    int stride = gridDim.x * blockDim.x;
    for (int e = blockIdx.x * blockDim.x + threadIdx.x; e < E; e += stride) {
        slot[e] = atomicAdd(&cnt[col[e]], 1);
    }
}

// ---- scan pass 1: per-256-chunk inclusive scan of cnt ----
__global__ __launch_bounds__(256) void scan_p1(const int* __restrict__ cnt,
                                               int* __restrict__ start,
                                               int* __restrict__ bsums, int N) {
    __shared__ int s[256];
    int tid = threadIdx.x;
    int i = blockIdx.x * 256 + tid;
    int v = (i < N) ? cnt[i] : 0;
    s[tid] = v;
    __syncthreads();
    for (int off = 1; off < 256; off <<= 1) {
        int t = (tid >= off) ? s[tid - off] : 0;
        __syncthreads();
        s[tid] += t;
        __syncthreads();
    }
    if (i < N) start[i] = s[tid];
    if (tid == 255) bsums[blockIdx.x] = s[255];
}

// ---- scan pass 2: exclusive scan of chunk sums ----
__global__ __launch_bounds__(1024) void scan_p2(int* __restrict__ bsums, int NB) {
    __shared__ int s[1024];
    int tid = threadIdx.x;
    int carry = 0;
    for (int base = 0; base < NB; base += 1024) {
        int i = base + tid;
        int v = (i < NB) ? bsums[i] : 0;
        s[tid] = v;
        __syncthreads();
        for (int off = 1; off < 1024; off <<= 1) {
            int t = (tid >= off) ? s[tid - off] : 0;
            __syncthreads();
            s[tid] += t;
            __syncthreads();
        }
        if (i < NB) bsums[i] = carry + s[tid] - v;
        int tot = s[1023];
        __syncthreads();
        carry += tot;
    }
}

// ---- scan pass 3: start -> exclusive global offsets; start[N] = E ----
__global__ __launch_bounds__(256) void scan_p3(int* __restrict__ start,
                                               const int* __restrict__ cnt,
                                               const int* __restrict__ bsums,
                                               int N, int E) {
    int i = blockIdx.x * 256 + threadIdx.x;
    if (i < N) start[i] += bsums[blockIdx.x] - cnt[i];
    if (i == 0) start[N] = E;
}

// ---- fill (NO atomics): csr[start[col]+slot] = {row, ea_bits} ----
__global__ void fill_kernel(const int* __restrict__ row, const int* __restrict__ col,
                            const float* __restrict__ ea, const int* __restrict__ slot,
                            const int* __restrict__ start,
                            int2* __restrict__ csr, int E) {
    int stride = gridDim.x * blockDim.x;
    for (int e = blockIdx.x * blockDim.x + threadIdx.x; e < E; e += stride) {
        int p = start[col[e]] + slot[e];
        csr[p] = make_int2(row[e], __float_as_int(ea[e]));
    }
}

// ---- deg+dis: contiguous segment sum of ea over CSR, then rsqrt ----
__global__ __launch_bounds__(256) void degdis_kernel(
        const int* __restrict__ start, const int2* __restrict__ csr,
        float* __restrict__ dis, int N) {
    int n = blockIdx.x * blockDim.x + threadIdx.x;
    if (n >= N) return;
    int e0 = start[n], e1 = start[n + 1];
    float d = 0.0f;
    for (int j = e0; j < e1; ++j) d += __int_as_float(csr[j].y);
    dis[n] = (d > 0.0f) ? rsqrtf(fmaxf(d, 1e-12f)) : 0.0f;
}

// ---- y = x @ W ----
__global__ __launch_bounds__(256) void lin_kernel(
        const float* __restrict__ x, const float* __restrict__ W,
        float* __restrict__ y, int N) {
    __shared__ float sW[FDIM * CDIM];
    for (int i = threadIdx.x; i < FDIM * CDIM; i += blockDim.x) sW[i] = W[i];
    __syncthreads();
    int n = blockIdx.x * blockDim.x + threadIdx.x;
    if (n >= N) return;
    float acc[CDIM];
    #pragma unroll
    for (int c = 0; c < CDIM; ++c) acc[c] = 0.0f;
    const float4* xr = (const float4*)(x + (size_t)n * FDIM);
    #pragma unroll
    for (int k4 = 0; k4 < FDIM / 4; ++k4) {
        float4 v = xr[k4];
        const float* wk = &sW[k4 * 4 * CDIM];
        #pragma unroll
        for (int c = 0; c < CDIM; ++c) acc[c] = fmaf(v.x, wk[c], acc[c]);
        #pragma unroll
        for (int c = 0; c < CDIM; ++c) acc[c] = fmaf(v.y, wk[CDIM + c], acc[c]);
        #pragma unroll
        for (int c = 0; c < CDIM; ++c) acc[c] = fmaf(v.z, wk[2 * CDIM + c], acc[c]);
        #pragma unroll
        for (int c = 0; c < CDIM; ++c) acc[c] = fmaf(v.w, wk[3 * CDIM + c], acc[c]);
    }
    float* yr = y + (size_t)n * CDIM;
    #pragma unroll
    for (int c = 0; c < CDIM; ++c) yr[c] = acc[c];
}

// ---- spmv: gout[n] = dis[n] * sum_j ea_j*dis[src_j] * gin[src_j]  ----
__global__ __launch_bounds__(256) void spmv_kernel(
        const float* __restrict__ gin, const int* __restrict__ start,
        const int2* __restrict__ csr, const float* __restrict__ dis,
        float* __restrict__ gout, int N) {
    int node = (blockIdx.x * blockDim.x + threadIdx.x) >> 6;
    int lane = threadIdx.x & 63;
    if (node >= N) return;
    int e0 = start[node], e1 = start[node + 1];
    float acc = 0.0f;
    int j = e0;
    for (; j + 1 < e1; j += 2) {
        int2 a = csr[j], b = csr[j + 1];
        float w0 = __int_as_float(a.y) * dis[a.x];
        float w1 = __int_as_float(b.y) * dis[b.x];
        if (lane < CDIM) {
            acc = fmaf(w0, gin[(size_t)a.x * CDIM + lane], acc);
            acc = fmaf(w1, gin[(size_t)b.x * CDIM + lane], acc);
        }
    }
    if (j < e1) {
        int2 a = csr[j];
        float w = __int_as_float(a.y) * dis[a.x];
        if (lane < CDIM) acc = fmaf(w, gin[(size_t)a.x * CDIM + lane], acc);
    }
    if (lane < CDIM) gout[(size_t)node * CDIM + lane] = dis[node] * acc;
}

// ---- conv2 + epilogue: log_softmax(0.05y + 0.475(g1+g2) + b) ----
__global__ __launch_bounds__(256) void spmv_final_kernel(
        const float* __restrict__ g1, const float* __restrict__ y,
        const float* __restrict__ bias, const int* __restrict__ start,
        const int2* __restrict__ csr, const float* __restrict__ dis,
        float* __restrict__ out, int N) {
    int node = (blockIdx.x * blockDim.x + threadIdx.x) >> 6;
    int lane = threadIdx.x & 63;
    if (node >= N) return;
    int e0 = start[node], e1 = start[node + 1];
    float acc = 0.0f;
    int j = e0;
    for (; j + 1 < e1; j += 2) {
        int2 a = csr[j], b = csr[j + 1];
        float w0 = __int_as_float(a.y) * dis[a.x];
        float w1 = __int_as_float(b.y) * dis[b.x];
        if (lane < CDIM) {
            acc = fmaf(w0, g1[(size_t)a.x * CDIM + lane], acc);
            acc = fmaf(w1, g1[(size_t)b.x * CDIM + lane], acc);
        }
    }
    if (j < e1) {
        int2 a = csr[j];
        float w = __int_as_float(a.y) * dis[a.x];
        if (lane < CDIM) acc = fmaf(w, g1[(size_t)a.x * CDIM + lane], acc);
    }
    float g2v = dis[node] * acc;
    float logit = 0.0f;
    if (lane < CDIM) {
        float yv  = y[(size_t)node * CDIM + lane];
        float g1v = g1[(size_t)node * CDIM + lane];
        logit = fmaf(ALPHA, yv, fmaf(SCALE, g1v + g2v, bias[lane]));
    }
    float ml = (lane < CDIM) ? logit : -INFINITY;
    #pragma unroll
    for (int off = 32; off; off >>= 1) ml = fmaxf(ml, __shfl_xor(ml, off));
    float ex = (lane < CDIM) ? expf(logit - ml) : 0.0f;
    #pragma unroll
    for (int off = 32; off; off >>= 1) ex += __shfl_xor(ex, off);
    float lse = ml + logf(ex);
    if (lane < CDIM) out[(size_t)node * CDIM + lane] = logit - lse;
}

extern "C" void kernel_launch(void* const* d_in, const int* in_sizes, int n_in,
                              void* d_out, int out_size, void* d_ws, size_t ws_size,
                              hipStream_t stream) {
    const float* x  = (const float*)d_in[0];   // [N,64]
    const float* ea = (const float*)d_in[1];   // [E]
    const float* W  = (const float*)d_in[2];   // [64,40]
    const float* b  = (const float*)d_in[3];   // [40]
    const int*   ei = (const int*)d_in[4];     // [2,E]: row then col

    const int N = in_sizes[0] / FDIM;
    const int E = in_sizes[1];
    const int* row = ei;
    const int* col = ei + E;
    const int NB = (N + 255) / 256;

    // workspace layout (4-byte units)
    int*   cnt   = (int*)d_ws;                   // NPAD
    int*   startp= cnt + NPAD;                   // NPAD (N+1 used)
    int*   bsums = startp + NPAD;                // 1024
    float* dis   = (float*)(bsums + 1024);       // NPAD
    int2*  csr   = (int2*)(dis + NPAD);          // E int2 (8B aligned: offset even)
    float* y     = (float*)(csr + E);            // N*CDIM   (slot aliases this)
    float* g1    = y + (size_t)N * CDIM;         // N*CDIM
    int*   slot  = (int*)y;                      // E ints, dead after fill

    hipMemsetAsync(cnt, 0, (size_t)NPAD * sizeof(int), stream);

    hist_kernel<<<2048, 256, 0, stream>>>(col, cnt, slot, E);
    scan_p1    <<<NB, 256, 0, stream>>>(cnt, startp, bsums, N);
    scan_p2    <<<1, 1024, 0, stream>>>(bsums, NB);
    scan_p3    <<<NB, 256, 0, stream>>>(startp, cnt, bsums, N, E);
    fill_kernel<<<2048, 256, 0, stream>>>(row, col, ea, slot, startp, csr, E);
    degdis_kernel<<<NB, 256, 0, stream>>>(startp, csr, dis, N);
    lin_kernel <<<NB, 256, 0, stream>>>(x, W, y, N);   // overwrites slot region

    int conv_blocks = (int)(((size_t)N * 64 + 255) / 256);
    spmv_kernel      <<<conv_blocks, 256, 0, stream>>>(y, startp, csr, dis, g1, N);
    spmv_final_kernel<<<conv_blocks, 256, 0, stream>>>(g1, y, b, startp, csr, dis,
                                                       (float*)d_out, N);
}

// Round 5
// 327.800 us; speedup vs baseline: 2.5622x; 1.1039x over previous
//
#include <hip/hip_runtime.h>
#include <math.h>

// piSGC R5: CSR-gather + bf16 payload tables.
//  - y and g1 stored as bf16 rows (80 B): gather = exactly 2 cache lines/edge,
//    tables 8 MB each (better L2 residency)
//  - csr weight pre-folded with dis[src] (csr_scale pass)
//  - 4-way unrolled gather loops, dual accumulators
//  - conv2 fused with log-softmax epilogue

#define ALPHA  0.05f
#define SCALE  0.475f   // (1 - ALPHA) / NUM_LAYERS
#define FDIM   64
#define CDIM   40
#define NPAD   131072

__device__ __forceinline__ float bf2f(unsigned short u) {
    return __uint_as_float(((unsigned)u) << 16);
}
__device__ __forceinline__ unsigned short f2bf(float f) {
    unsigned u = __float_as_uint(f);
    unsigned r = (u + 0x7FFFu + ((u >> 16) & 1u)) >> 16;   // round-nearest-even
    return (unsigned short)r;
}

// ---- hist: slot[e] = cnt[col[e]]++  ----
__global__ void hist_kernel(const int* __restrict__ col,
                            int* __restrict__ cnt,
                            int* __restrict__ slot, int E) {
    int stride = gridDim.x * blockDim.x;
    for (int e = blockIdx.x * blockDim.x + threadIdx.x; e < E; e += stride) {
        slot[e] = atomicAdd(&cnt[col[e]], 1);
    }
}

// ---- scan pass 1 ----
__global__ __launch_bounds__(256) void scan_p1(const int* __restrict__ cnt,
                                               int* __restrict__ start,
                                               int* __restrict__ bsums, int N) {
    __shared__ int s[256];
    int tid = threadIdx.x;
    int i = blockIdx.x * 256 + tid;
    int v = (i < N) ? cnt[i] : 0;
    s[tid] = v;
    __syncthreads();
    for (int off = 1; off < 256; off <<= 1) {
        int t = (tid >= off) ? s[tid - off] : 0;
        __syncthreads();
        s[tid] += t;
        __syncthreads();
    }
    if (i < N) start[i] = s[tid];
    if (tid == 255) bsums[blockIdx.x] = s[255];
}

// ---- scan pass 2 ----
__global__ __launch_bounds__(1024) void scan_p2(int* __restrict__ bsums, int NB) {
    __shared__ int s[1024];
    int tid = threadIdx.x;
    int carry = 0;
    for (int base = 0; base < NB; base += 1024) {
        int i = base + tid;
        int v = (i < NB) ? bsums[i] : 0;
        s[tid] = v;
        __syncthreads();
        for (int off = 1; off < 1024; off <<= 1) {
            int t = (tid >= off) ? s[tid - off] : 0;
            __syncthreads();
            s[tid] += t;
            __syncthreads();
        }
        if (i < NB) bsums[i] = carry + s[tid] - v;
        int tot = s[1023];
        __syncthreads();
        carry += tot;
    }
}

// ---- scan pass 3 ----
__global__ __launch_bounds__(256) void scan_p3(int* __restrict__ start,
                                               const int* __restrict__ cnt,
                                               const int* __restrict__ bsums,
                                               int N, int E) {
    int i = blockIdx.x * 256 + threadIdx.x;
    if (i < N) start[i] += bsums[blockIdx.x] - cnt[i];
    if (i == 0) start[N] = E;
}

// ---- fill (no atomics): csr[start[col]+slot] = {row, ea_bits} ----
__global__ void fill_kernel(const int* __restrict__ row, const int* __restrict__ col,
                            const float* __restrict__ ea, const int* __restrict__ slot,
                            const int* __restrict__ start,
                            int2* __restrict__ csr, int E) {
    int stride = gridDim.x * blockDim.x;
    for (int e = blockIdx.x * blockDim.x + threadIdx.x; e < E; e += stride) {
        int p = start[col[e]] + slot[e];
        csr[p] = make_int2(row[e], __float_as_int(ea[e]));
    }
}

// ---- deg+dis: segment sum of raw ea over CSR, then rsqrt ----
__global__ __launch_bounds__(256) void degdis_kernel(
        const int* __restrict__ start, const int2* __restrict__ csr,
        float* __restrict__ dis, int N) {
    int n = blockIdx.x * blockDim.x + threadIdx.x;
    if (n >= N) return;
    int e0 = start[n], e1 = start[n + 1];
    float d = 0.0f;
    for (int j = e0; j < e1; ++j) d += __int_as_float(csr[j].y);
    dis[n] = (d > 0.0f) ? rsqrtf(fmaxf(d, 1e-12f)) : 0.0f;
}

// ---- fold dis[src] into csr weight ----
__global__ void csr_scale_kernel(int2* __restrict__ csr,
                                 const float* __restrict__ dis, int E) {
    int stride = gridDim.x * blockDim.x;
    for (int e = blockIdx.x * blockDim.x + threadIdx.x; e < E; e += stride) {
        int2 a = csr[e];
        a.y = __float_as_int(__int_as_float(a.y) * dis[a.x]);
        csr[e] = a;
    }
}

// ---- y = x @ W, stored bf16 (packed uint, 20 per node) ----
__global__ __launch_bounds__(256) void lin_kernel(
        const float* __restrict__ x, const float* __restrict__ W,
        unsigned* __restrict__ ybf, int N) {
    __shared__ float sW[FDIM * CDIM];
    for (int i = threadIdx.x; i < FDIM * CDIM; i += blockDim.x) sW[i] = W[i];
    __syncthreads();
    int n = blockIdx.x * blockDim.x + threadIdx.x;
    if (n >= N) return;
    float acc[CDIM];
    #pragma unroll
    for (int c = 0; c < CDIM; ++c) acc[c] = 0.0f;
    const float4* xr = (const float4*)(x + (size_t)n * FDIM);
    #pragma unroll
    for (int k4 = 0; k4 < FDIM / 4; ++k4) {
        float4 v = xr[k4];
        const float* wk = &sW[k4 * 4 * CDIM];
        #pragma unroll
        for (int c = 0; c < CDIM; ++c) acc[c] = fmaf(v.x, wk[c], acc[c]);
        #pragma unroll
        for (int c = 0; c < CDIM; ++c) acc[c] = fmaf(v.y, wk[CDIM + c], acc[c]);
        #pragma unroll
        for (int c = 0; c < CDIM; ++c) acc[c] = fmaf(v.z, wk[2 * CDIM + c], acc[c]);
        #pragma unroll
        for (int c = 0; c < CDIM; ++c) acc[c] = fmaf(v.w, wk[3 * CDIM + c], acc[c]);
    }
    unsigned* yr = ybf + (size_t)n * (CDIM / 2);
    #pragma unroll
    for (int k = 0; k < CDIM / 2; ++k)
        yr[k] = (unsigned)f2bf(acc[2 * k]) | ((unsigned)f2bf(acc[2 * k + 1]) << 16);
}

// ---- spmv1: g1[n] = dis[n] * sum_j w_j * y[src_j]   (bf16 in, bf16 out) ----
__global__ __launch_bounds__(256) void spmv_kernel(
        const unsigned short* __restrict__ gin, const int* __restrict__ start,
        const int2* __restrict__ csr, const float* __restrict__ dis,
        unsigned short* __restrict__ gout, int N) {
    int node = (blockIdx.x * blockDim.x + threadIdx.x) >> 6;
    int lane = threadIdx.x & 63;
    if (node >= N) return;
    int e0 = start[node], e1 = start[node + 1];
    float acc0 = 0.0f, acc1 = 0.0f;
    int j = e0;
    for (; j + 3 < e1; j += 4) {
        int2 a = csr[j], b = csr[j + 1], c = csr[j + 2], d = csr[j + 3];
        if (lane < CDIM) {
            acc0 = fmaf(__int_as_float(a.y), bf2f(gin[(size_t)a.x * CDIM + lane]), acc0);
            acc1 = fmaf(__int_as_float(b.y), bf2f(gin[(size_t)b.x * CDIM + lane]), acc1);
            acc0 = fmaf(__int_as_float(c.y), bf2f(gin[(size_t)c.x * CDIM + lane]), acc0);
            acc1 = fmaf(__int_as_float(d.y), bf2f(gin[(size_t)d.x * CDIM + lane]), acc1);
        }
    }
    for (; j < e1; ++j) {
        int2 a = csr[j];
        if (lane < CDIM)
            acc0 = fmaf(__int_as_float(a.y), bf2f(gin[(size_t)a.x * CDIM + lane]), acc0);
    }
    if (lane < CDIM)
        gout[(size_t)node * CDIM + lane] = f2bf(dis[node] * (acc0 + acc1));
}

// ---- conv2 + epilogue: log_softmax(0.05y + 0.475(g1+g2) + b) ----
__global__ __launch_bounds__(256) void spmv_final_kernel(
        const unsigned short* __restrict__ g1, const unsigned short* __restrict__ y,
        const float* __restrict__ bias, const int* __restrict__ start,
        const int2* __restrict__ csr, const float* __restrict__ dis,
        float* __restrict__ out, int N) {
    int node = (blockIdx.x * blockDim.x + threadIdx.x) >> 6;
    int lane = threadIdx.x & 63;
    if (node >= N) return;
    int e0 = start[node], e1 = start[node + 1];
    float acc0 = 0.0f, acc1 = 0.0f;
    int j = e0;
    for (; j + 3 < e1; j += 4) {
        int2 a = csr[j], b = csr[j + 1], c = csr[j + 2], d = csr[j + 3];
        if (lane < CDIM) {
            acc0 = fmaf(__int_as_float(a.y), bf2f(g1[(size_t)a.x * CDIM + lane]), acc0);
            acc1 = fmaf(__int_as_float(b.y), bf2f(g1[(size_t)b.x * CDIM + lane]), acc1);
            acc0 = fmaf(__int_as_float(c.y), bf2f(g1[(size_t)c.x * CDIM + lane]), acc0);
            acc1 = fmaf(__int_as_float(d.y), bf2f(g1[(size_t)d.x * CDIM + lane]), acc1);
        }
    }
    for (; j < e1; ++j) {
        int2 a = csr[j];
        if (lane < CDIM)
            acc0 = fmaf(__int_as_float(a.y), bf2f(g1[(size_t)a.x * CDIM + lane]), acc0);
    }
    float g2v = dis[node] * (acc0 + acc1);
    float logit = 0.0f;
    if (lane < CDIM) {
        float yv  = bf2f(y[(size_t)node * CDIM + lane]);
        float g1v = bf2f(g1[(size_t)node * CDIM + lane]);
        logit = fmaf(ALPHA, yv, fmaf(SCALE, g1v + g2v, bias[lane]));
    }
    float ml = (lane < CDIM) ? logit : -INFINITY;
    #pragma unroll
    for (int off = 32; off; off >>= 1) ml = fmaxf(ml, __shfl_xor(ml, off));
    float ex = (lane < CDIM) ? expf(logit - ml) : 0.0f;
    #pragma unroll
    for (int off = 32; off; off >>= 1) ex += __shfl_xor(ex, off);
    float lse = ml + logf(ex);
    if (lane < CDIM) out[(size_t)node * CDIM + lane] = logit - lse;
}

extern "C" void kernel_launch(void* const* d_in, const int* in_sizes, int n_in,
                              void* d_out, int out_size, void* d_ws, size_t ws_size,
                              hipStream_t stream) {
    const float* x  = (const float*)d_in[0];   // [N,64]
    const float* ea = (const float*)d_in[1];   // [E]
    const float* W  = (const float*)d_in[2];   // [64,40]
    const float* b  = (const float*)d_in[3];   // [40]
    const int*   ei = (const int*)d_in[4];     // [2,E]: row then col

    const int N = in_sizes[0] / FDIM;
    const int E = in_sizes[1];
    const int* row = ei;
    const int* col = ei + E;
    const int NB = (N + 255) / 256;

    // workspace layout (4-byte units unless noted)
    int*   cnt   = (int*)d_ws;                     // NPAD
    int*   startp= cnt + NPAD;                     // NPAD (N+1 used)
    int*   bsums = startp + NPAD;                  // 1024
    float* dis   = (float*)(bsums + 1024);         // NPAD
    int2*  csr   = (int2*)(dis + NPAD);            // E int2
    unsigned* ybf  = (unsigned*)(csr + E);         // N*20 uints (bf16 y), aliased by slot
    unsigned* g1bf = ybf + (size_t)N * (CDIM / 2); // N*20 uints (bf16 g1)
    int*   slot  = (int*)ybf;                      // E ints, dead after fill

    hipMemsetAsync(cnt, 0, (size_t)NPAD * sizeof(int), stream);

    hist_kernel<<<2048, 256, 0, stream>>>(col, cnt, slot, E);
    scan_p1    <<<NB, 256, 0, stream>>>(cnt, startp, bsums, N);
    scan_p2    <<<1, 1024, 0, stream>>>(bsums, NB);
    scan_p3    <<<NB, 256, 0, stream>>>(startp, cnt, bsums, N, E);
    fill_kernel<<<2048, 256, 0, stream>>>(row, col, ea, slot, startp, csr, E);
    degdis_kernel<<<NB, 256, 0, stream>>>(startp, csr, dis, N);
    csr_scale_kernel<<<2048, 256, 0, stream>>>(csr, dis, E);
    lin_kernel <<<NB, 256, 0, stream>>>(x, W, ybf, N);   // overwrites slot region

    int conv_blocks = (int)(((size_t)N * 64 + 255) / 256);
    spmv_kernel      <<<conv_blocks, 256, 0, stream>>>((const unsigned short*)ybf,
                          startp, csr, dis, (unsigned short*)g1bf, N);
    spmv_final_kernel<<<conv_blocks, 256, 0, stream>>>((const unsigned short*)g1bf,
                          (const unsigned short*)ybf, b, startp, csr, dis,
                          (float*)d_out, N);
}

// Round 6
// 254.743 us; speedup vs baseline: 3.2970x; 1.2868x over previous
//
#include <hip/hip_runtime.h>
#include <math.h>

// piSGC R6: CSR-gather + bf16 payload tables.
//  - lin: 4 threads/node x 10 outputs, W^T in padded LDS -> 4x parallelism
//  - spmv: wave-uniform node via readfirstlane (scalar csr/start/dis loads),
//    8-wide unrolled gather loop with 4 accumulators
//  - conv2 fused with log-softmax epilogue

#define ALPHA  0.05f
#define SCALE  0.475f   // (1 - ALPHA) / NUM_LAYERS
#define FDIM   64
#define CDIM   40
#define NPAD   131072

__device__ __forceinline__ float bf2f(unsigned short u) {
    return __uint_as_float(((unsigned)u) << 16);
}
__device__ __forceinline__ unsigned short f2bf(float f) {
    unsigned u = __float_as_uint(f);
    unsigned r = (u + 0x7FFFu + ((u >> 16) & 1u)) >> 16;   // round-nearest-even
    return (unsigned short)r;
}

// ---- hist: slot[e] = cnt[col[e]]++  ----
__global__ void hist_kernel(const int* __restrict__ col,
                            int* __restrict__ cnt,
                            int* __restrict__ slot, int E) {
    int stride = gridDim.x * blockDim.x;
    for (int e = blockIdx.x * blockDim.x + threadIdx.x; e < E; e += stride) {
        slot[e] = atomicAdd(&cnt[col[e]], 1);
    }
}

// ---- scan pass 1 ----
__global__ __launch_bounds__(256) void scan_p1(const int* __restrict__ cnt,
                                               int* __restrict__ start,
                                               int* __restrict__ bsums, int N) {
    __shared__ int s[256];
    int tid = threadIdx.x;
    int i = blockIdx.x * 256 + tid;
    int v = (i < N) ? cnt[i] : 0;
    s[tid] = v;
    __syncthreads();
    for (int off = 1; off < 256; off <<= 1) {
        int t = (tid >= off) ? s[tid - off] : 0;
        __syncthreads();
        s[tid] += t;
        __syncthreads();
    }
    if (i < N) start[i] = s[tid];
    if (tid == 255) bsums[blockIdx.x] = s[255];
}

// ---- scan pass 2 ----
__global__ __launch_bounds__(1024) void scan_p2(int* __restrict__ bsums, int NB) {
    __shared__ int s[1024];
    int tid = threadIdx.x;
    int carry = 0;
    for (int base = 0; base < NB; base += 1024) {
        int i = base + tid;
        int v = (i < NB) ? bsums[i] : 0;
        s[tid] = v;
        __syncthreads();
        for (int off = 1; off < 1024; off <<= 1) {
            int t = (tid >= off) ? s[tid - off] : 0;
            __syncthreads();
            s[tid] += t;
            __syncthreads();
        }
        if (i < NB) bsums[i] = carry + s[tid] - v;
        int tot = s[1023];
        __syncthreads();
        carry += tot;
    }
}

// ---- scan pass 3 ----
__global__ __launch_bounds__(256) void scan_p3(int* __restrict__ start,
                                               const int* __restrict__ cnt,
                                               const int* __restrict__ bsums,
                                               int N, int E) {
    int i = blockIdx.x * 256 + threadIdx.x;
    if (i < N) start[i] += bsums[blockIdx.x] - cnt[i];
    if (i == 0) start[N] = E;
}

// ---- fill (no atomics): csr[start[col]+slot] = {row, ea_bits} ----
__global__ void fill_kernel(const int* __restrict__ row, const int* __restrict__ col,
                            const float* __restrict__ ea, const int* __restrict__ slot,
                            const int* __restrict__ start,
                            int2* __restrict__ csr, int E) {
    int stride = gridDim.x * blockDim.x;
    for (int e = blockIdx.x * blockDim.x + threadIdx.x; e < E; e += stride) {
        int p = start[col[e]] + slot[e];
        csr[p] = make_int2(row[e], __float_as_int(ea[e]));
    }
}

// ---- deg+dis: segment sum of raw ea over CSR, then rsqrt ----
__global__ __launch_bounds__(256) void degdis_kernel(
        const int* __restrict__ start, const int2* __restrict__ csr,
        float* __restrict__ dis, int N) {
    int n = blockIdx.x * blockDim.x + threadIdx.x;
    if (n >= N) return;
    int e0 = start[n], e1 = start[n + 1];
    float d = 0.0f;
    for (int j = e0; j < e1; ++j) d += __int_as_float(csr[j].y);
    dis[n] = (d > 0.0f) ? rsqrtf(fmaxf(d, 1e-12f)) : 0.0f;
}

// ---- fold dis[src] into csr weight ----
__global__ void csr_scale_kernel(int2* __restrict__ csr,
                                 const float* __restrict__ dis, int E) {
    int stride = gridDim.x * blockDim.x;
    for (int e = blockIdx.x * blockDim.x + threadIdx.x; e < E; e += stride) {
        int2 a = csr[e];
        a.y = __float_as_int(__int_as_float(a.y) * dis[a.x]);
        csr[e] = a;
    }
}

// ---- y = x @ W, bf16 packed. 4 threads/node x 10 outputs, 64 nodes/block ----
__global__ __launch_bounds__(256) void lin_kernel(
        const float* __restrict__ x, const float* __restrict__ W,
        unsigned* __restrict__ ybf, int N) {
    __shared__ float sWt[CDIM][FDIM + 4];   // transposed, stride 68 (16B-aligned rows)
    for (int i = threadIdx.x; i < FDIM * CDIM; i += 256) {
        int k = i / CDIM, c = i - k * CDIM;
        sWt[c][k] = W[i];
    }
    __syncthreads();

    int t = threadIdx.x;
    int node = blockIdx.x * 64 + (t >> 2);
    if (node >= N) return;
    int cs = (t & 3) * 10;

    float acc[10];
    #pragma unroll
    for (int i = 0; i < 10; ++i) acc[i] = 0.0f;

    const float4* xr = (const float4*)(x + (size_t)node * FDIM);
    #pragma unroll
    for (int k4 = 0; k4 < FDIM / 4; ++k4) {
        float4 v = xr[k4];
        #pragma unroll
        for (int i = 0; i < 10; ++i) {
            const float4 w = *(const float4*)&sWt[cs + i][k4 * 4];
            acc[i] = fmaf(v.x, w.x, fmaf(v.y, w.y, fmaf(v.z, w.z, fmaf(v.w, w.w, acc[i]))));
        }
    }

    unsigned* yr = ybf + (size_t)node * (CDIM / 2) + (t & 3) * 5;
    #pragma unroll
    for (int k = 0; k < 5; ++k)
        yr[k] = (unsigned)f2bf(acc[2 * k]) | ((unsigned)f2bf(acc[2 * k + 1]) << 16);
}

// ---- spmv1: g1[n] = dis[n] * sum_j w_j * y[src_j]   (bf16 in, bf16 out) ----
__global__ __launch_bounds__(256) void spmv_kernel(
        const unsigned short* __restrict__ gin, const int* __restrict__ start,
        const int2* __restrict__ csr, const float* __restrict__ dis,
        unsigned short* __restrict__ gout, int N) {
    int node = (blockIdx.x * blockDim.x + threadIdx.x) >> 6;
    node = __builtin_amdgcn_readfirstlane(node);      // wave-uniform -> SMEM loads
    int lane = threadIdx.x & 63;
    if (node >= N) return;
    int e0 = start[node], e1 = start[node + 1];
    float acc0 = 0.0f, acc1 = 0.0f, acc2 = 0.0f, acc3 = 0.0f;
    int j = e0;
    for (; j + 7 < e1; j += 8) {
        int2 c0 = csr[j],     c1 = csr[j + 1], c2 = csr[j + 2], c3 = csr[j + 3];
        int2 c4 = csr[j + 4], c5 = csr[j + 5], c6 = csr[j + 6], c7 = csr[j + 7];
        if (lane < CDIM) {
            acc0 = fmaf(__int_as_float(c0.y), bf2f(gin[(size_t)c0.x * CDIM + lane]), acc0);
            acc1 = fmaf(__int_as_float(c1.y), bf2f(gin[(size_t)c1.x * CDIM + lane]), acc1);
            acc2 = fmaf(__int_as_float(c2.y), bf2f(gin[(size_t)c2.x * CDIM + lane]), acc2);
            acc3 = fmaf(__int_as_float(c3.y), bf2f(gin[(size_t)c3.x * CDIM + lane]), acc3);
            acc0 = fmaf(__int_as_float(c4.y), bf2f(gin[(size_t)c4.x * CDIM + lane]), acc0);
            acc1 = fmaf(__int_as_float(c5.y), bf2f(gin[(size_t)c5.x * CDIM + lane]), acc1);
            acc2 = fmaf(__int_as_float(c6.y), bf2f(gin[(size_t)c6.x * CDIM + lane]), acc2);
            acc3 = fmaf(__int_as_float(c7.y), bf2f(gin[(size_t)c7.x * CDIM + lane]), acc3);
        }
    }
    for (; j < e1; ++j) {
        int2 a = csr[j];
        if (lane < CDIM)
            acc0 = fmaf(__int_as_float(a.y), bf2f(gin[(size_t)a.x * CDIM + lane]), acc0);
    }
    if (lane < CDIM)
        gout[(size_t)node * CDIM + lane] = f2bf(dis[node] * ((acc0 + acc1) + (acc2 + acc3)));
}

// ---- conv2 + epilogue: log_softmax(0.05y + 0.475(g1+g2) + b) ----
__global__ __launch_bounds__(256) void spmv_final_kernel(
        const unsigned short* __restrict__ g1, const unsigned short* __restrict__ y,
        const float* __restrict__ bias, const int* __restrict__ start,
        const int2* __restrict__ csr, const float* __restrict__ dis,
        float* __restrict__ out, int N) {
    int node = (blockIdx.x * blockDim.x + threadIdx.x) >> 6;
    node = __builtin_amdgcn_readfirstlane(node);
    int lane = threadIdx.x & 63;
    if (node >= N) return;
    int e0 = start[node], e1 = start[node + 1];
    float acc0 = 0.0f, acc1 = 0.0f, acc2 = 0.0f, acc3 = 0.0f;
    int j = e0;
    for (; j + 7 < e1; j += 8) {
        int2 c0 = csr[j],     c1 = csr[j + 1], c2 = csr[j + 2], c3 = csr[j + 3];
        int2 c4 = csr[j + 4], c5 = csr[j + 5], c6 = csr[j + 6], c7 = csr[j + 7];
        if (lane < CDIM) {
            acc0 = fmaf(__int_as_float(c0.y), bf2f(g1[(size_t)c0.x * CDIM + lane]), acc0);
            acc1 = fmaf(__int_as_float(c1.y), bf2f(g1[(size_t)c1.x * CDIM + lane]), acc1);
            acc2 = fmaf(__int_as_float(c2.y), bf2f(g1[(size_t)c2.x * CDIM + lane]), acc2);
            acc3 = fmaf(__int_as_float(c3.y), bf2f(g1[(size_t)c3.x * CDIM + lane]), acc3);
            acc0 = fmaf(__int_as_float(c4.y), bf2f(g1[(size_t)c4.x * CDIM + lane]), acc0);
            acc1 = fmaf(__int_as_float(c5.y), bf2f(g1[(size_t)c5.x * CDIM + lane]), acc1);
            acc2 = fmaf(__int_as_float(c6.y), bf2f(g1[(size_t)c6.x * CDIM + lane]), acc2);
            acc3 = fmaf(__int_as_float(c7.y), bf2f(g1[(size_t)c7.x * CDIM + lane]), acc3);
        }
    }
    for (; j < e1; ++j) {
        int2 a = csr[j];
        if (lane < CDIM)
            acc0 = fmaf(__int_as_float(a.y), bf2f(g1[(size_t)a.x * CDIM + lane]), acc0);
    }
    float g2v = dis[node] * ((acc0 + acc1) + (acc2 + acc3));
    float logit = 0.0f;
    if (lane < CDIM) {
        float yv  = bf2f(y[(size_t)node * CDIM + lane]);
        float g1v = bf2f(g1[(size_t)node * CDIM + lane]);
        logit = fmaf(ALPHA, yv, fmaf(SCALE, g1v + g2v, bias[lane]));
    }
    float ml = (lane < CDIM) ? logit : -INFINITY;
    #pragma unroll
    for (int off = 32; off; off >>= 1) ml = fmaxf(ml, __shfl_xor(ml, off));
    float ex = (lane < CDIM) ? expf(logit - ml) : 0.0f;
    #pragma unroll
    for (int off = 32; off; off >>= 1) ex += __shfl_xor(ex, off);
    float lse = ml + logf(ex);
    if (lane < CDIM) out[(size_t)node * CDIM + lane] = logit - lse;
}

extern "C" void kernel_launch(void* const* d_in, const int* in_sizes, int n_in,
                              void* d_out, int out_size, void* d_ws, size_t ws_size,
                              hipStream_t stream) {
    const float* x  = (const float*)d_in[0];   // [N,64]
    const float* ea = (const float*)d_in[1];   // [E]
    const float* W  = (const float*)d_in[2];   // [64,40]
    const float* b  = (const float*)d_in[3];   // [40]
    const int*   ei = (const int*)d_in[4];     // [2,E]: row then col

    const int N = in_sizes[0] / FDIM;
    const int E = in_sizes[1];
    const int* row = ei;
    const int* col = ei + E;
    const int NB = (N + 255) / 256;

    // workspace layout (4-byte units unless noted)
    int*   cnt   = (int*)d_ws;                     // NPAD
    int*   startp= cnt + NPAD;                     // NPAD (N+1 used)
    int*   bsums = startp + NPAD;                  // 1024
    float* dis   = (float*)(bsums + 1024);         // NPAD
    int2*  csr   = (int2*)(dis + NPAD);            // E int2
    unsigned* ybf  = (unsigned*)(csr + E);         // N*20 uints (bf16 y), aliased by slot
    unsigned* g1bf = ybf + (size_t)N * (CDIM / 2); // N*20 uints (bf16 g1)
    int*   slot  = (int*)ybf;                      // E ints, dead after fill

    hipMemsetAsync(cnt, 0, (size_t)NPAD * sizeof(int), stream);

    hist_kernel<<<2048, 256, 0, stream>>>(col, cnt, slot, E);
    scan_p1    <<<NB, 256, 0, stream>>>(cnt, startp, bsums, N);
    scan_p2    <<<1, 1024, 0, stream>>>(bsums, NB);
    scan_p3    <<<NB, 256, 0, stream>>>(startp, cnt, bsums, N, E);
    fill_kernel<<<2048, 256, 0, stream>>>(row, col, ea, slot, startp, csr, E);
    degdis_kernel<<<NB, 256, 0, stream>>>(startp, csr, dis, N);
    csr_scale_kernel<<<2048, 256, 0, stream>>>(csr, dis, E);
    lin_kernel <<<(N + 63) / 64, 256, 0, stream>>>(x, W, ybf, N);   // overwrites slot region

    int conv_blocks = (int)(((size_t)N * 64 + 255) / 256);
    spmv_kernel      <<<conv_blocks, 256, 0, stream>>>((const unsigned short*)ybf,
                          startp, csr, dis, (unsigned short*)g1bf, N);
    spmv_final_kernel<<<conv_blocks, 256, 0, stream>>>((const unsigned short*)g1bf,
                          (const unsigned short*)ybf, b, startp, csr, dis,
                          (float*)d_out, N);
}

// Round 7
// 230.549 us; speedup vs baseline: 3.6429x; 1.1049x over previous
//
#include <hip/hip_runtime.h>
#include <math.h>

// piSGC R7: CSR-gather, bf16x2-packed payload, 3-nodes-per-wave spmv.
//  - hist: 4 edges/thread, int4 load, 4 independent atomics (latency amortize)
//  - spmv: 20 lanes per node (dword = 2 bf16 features), 3 nodes/wave,
//    4-deep unrolled gather -> 12 edge-gathers in flight per wave
//  - spmv_final: same + group-shuffle log-softmax epilogue, float2 stores

#define ALPHA  0.05f
#define SCALE  0.475f   // (1 - ALPHA) / NUM_LAYERS
#define FDIM   64
#define CDIM   40
#define NPAD   131072

__device__ __forceinline__ unsigned short f2bf(float f) {
    unsigned u = __float_as_uint(f);
    unsigned r = (u + 0x7FFFu + ((u >> 16) & 1u)) >> 16;   // round-nearest-even
    return (unsigned short)r;
}
__device__ __forceinline__ float bfLo(unsigned u) { return __uint_as_float(u << 16); }
__device__ __forceinline__ float bfHi(unsigned u) { return __uint_as_float(u & 0xffff0000u); }

// ---- hist: slot[e] = cnt[col[e]]++ , 4 edges/thread ----
__global__ __launch_bounds__(256) void hist_kernel(const int* __restrict__ col,
                                                   int* __restrict__ cnt,
                                                   int* __restrict__ slot, int E) {
    int t = blockIdx.x * blockDim.x + threadIdx.x;
    int base = t * 4;
    if (base + 3 < E) {
        int4 c = *(const int4*)&col[base];
        int4 s;
        s.x = atomicAdd(&cnt[c.x], 1);
        s.y = atomicAdd(&cnt[c.y], 1);
        s.z = atomicAdd(&cnt[c.z], 1);
        s.w = atomicAdd(&cnt[c.w], 1);
        *(int4*)&slot[base] = s;
    } else {
        for (int e = base; e < E; ++e)
            slot[e] = atomicAdd(&cnt[col[e]], 1);
    }
}

// ---- scan pass 1 ----
__global__ __launch_bounds__(256) void scan_p1(const int* __restrict__ cnt,
                                               int* __restrict__ start,
                                               int* __restrict__ bsums, int N) {
    __shared__ int s[256];
    int tid = threadIdx.x;
    int i = blockIdx.x * 256 + tid;
    int v = (i < N) ? cnt[i] : 0;
    s[tid] = v;
    __syncthreads();
    for (int off = 1; off < 256; off <<= 1) {
        int t = (tid >= off) ? s[tid - off] : 0;
        __syncthreads();
        s[tid] += t;
        __syncthreads();
    }
    if (i < N) start[i] = s[tid];
    if (tid == 255) bsums[blockIdx.x] = s[255];
}

// ---- scan pass 2 ----
__global__ __launch_bounds__(1024) void scan_p2(int* __restrict__ bsums, int NB) {
    __shared__ int s[1024];
    int tid = threadIdx.x;
    int carry = 0;
    for (int base = 0; base < NB; base += 1024) {
        int i = base + tid;
        int v = (i < NB) ? bsums[i] : 0;
        s[tid] = v;
        __syncthreads();
        for (int off = 1; off < 1024; off <<= 1) {
            int t = (tid >= off) ? s[tid - off] : 0;
            __syncthreads();
            s[tid] += t;
            __syncthreads();
        }
        if (i < NB) bsums[i] = carry + s[tid] - v;
        int tot = s[1023];
        __syncthreads();
        carry += tot;
    }
}

// ---- scan pass 3 ----
__global__ __launch_bounds__(256) void scan_p3(int* __restrict__ start,
                                               const int* __restrict__ cnt,
                                               const int* __restrict__ bsums,
                                               int N, int E) {
    int i = blockIdx.x * 256 + threadIdx.x;
    if (i < N) start[i] += bsums[blockIdx.x] - cnt[i];
    if (i == 0) start[N] = E;
}

// ---- fill (no atomics): csr[start[col]+slot] = {row, ea_bits} ----
__global__ void fill_kernel(const int* __restrict__ row, const int* __restrict__ col,
                            const float* __restrict__ ea, const int* __restrict__ slot,
                            const int* __restrict__ start,
                            int2* __restrict__ csr, int E) {
    int stride = gridDim.x * blockDim.x;
    for (int e = blockIdx.x * blockDim.x + threadIdx.x; e < E; e += stride) {
        int p = start[col[e]] + slot[e];
        csr[p] = make_int2(row[e], __float_as_int(ea[e]));
    }
}

// ---- deg+dis: segment sum of raw ea over CSR, then rsqrt ----
__global__ __launch_bounds__(256) void degdis_kernel(
        const int* __restrict__ start, const int2* __restrict__ csr,
        float* __restrict__ dis, int N) {
    int n = blockIdx.x * blockDim.x + threadIdx.x;
    if (n >= N) return;
    int e0 = start[n], e1 = start[n + 1];
    float d = 0.0f;
    for (int j = e0; j < e1; ++j) d += __int_as_float(csr[j].y);
    dis[n] = (d > 0.0f) ? rsqrtf(fmaxf(d, 1e-12f)) : 0.0f;
}

// ---- fold dis[src] into csr weight ----
__global__ void csr_scale_kernel(int2* __restrict__ csr,
                                 const float* __restrict__ dis, int E) {
    int stride = gridDim.x * blockDim.x;
    for (int e = blockIdx.x * blockDim.x + threadIdx.x; e < E; e += stride) {
        int2 a = csr[e];
        a.y = __float_as_int(__int_as_float(a.y) * dis[a.x]);
        csr[e] = a;
    }
}

// ---- y = x @ W, bf16 packed. 4 threads/node x 10 outputs, 64 nodes/block ----
__global__ __launch_bounds__(256) void lin_kernel(
        const float* __restrict__ x, const float* __restrict__ W,
        unsigned* __restrict__ ybf, int N) {
    __shared__ float sWt[CDIM][FDIM + 4];
    for (int i = threadIdx.x; i < FDIM * CDIM; i += 256) {
        int k = i / CDIM, c = i - k * CDIM;
        sWt[c][k] = W[i];
    }
    __syncthreads();

    int t = threadIdx.x;
    int node = blockIdx.x * 64 + (t >> 2);
    if (node >= N) return;
    int cs = (t & 3) * 10;

    float acc[10];
    #pragma unroll
    for (int i = 0; i < 10; ++i) acc[i] = 0.0f;

    const float4* xr = (const float4*)(x + (size_t)node * FDIM);
    #pragma unroll
    for (int k4 = 0; k4 < FDIM / 4; ++k4) {
        float4 v = xr[k4];
        #pragma unroll
        for (int i = 0; i < 10; ++i) {
            const float4 w = *(const float4*)&sWt[cs + i][k4 * 4];
            acc[i] = fmaf(v.x, w.x, fmaf(v.y, w.y, fmaf(v.z, w.z, fmaf(v.w, w.w, acc[i]))));
        }
    }

    unsigned* yr = ybf + (size_t)node * (CDIM / 2) + (t & 3) * 5;
    #pragma unroll
    for (int k = 0; k < 5; ++k)
        yr[k] = (unsigned)f2bf(acc[2 * k]) | ((unsigned)f2bf(acc[2 * k + 1]) << 16);
}

// ---- spmv1: g1[n] = dis[n] * sum_j w_j * y[src_j]; 3 nodes/wave, 20 lanes each ----
__global__ __launch_bounds__(256) void spmv_kernel(
        const unsigned* __restrict__ gin, const int* __restrict__ start,
        const int2* __restrict__ csr, const float* __restrict__ dis,
        unsigned* __restrict__ gout, int N) {
    int lane = threadIdx.x & 63;
    int wid  = threadIdx.x >> 6;
    int grp  = lane / 20;            // 0,1,2 active; 3 idle
    int grel = lane - grp * 20;
    int node = blockIdx.x * 12 + wid * 3 + grp;
    bool act = (grp < 3) && (node < N);

    int e0 = 0, e1 = 0;
    if (act) { e0 = start[node]; e1 = start[node + 1]; }

    float aL0 = 0, aL1 = 0, aL2 = 0, aL3 = 0;
    float aH0 = 0, aH1 = 0, aH2 = 0, aH3 = 0;
    int j = e0;
    for (; j + 3 < e1; j += 4) {
        int2 c0 = csr[j], c1 = csr[j + 1], c2 = csr[j + 2], c3 = csr[j + 3];
        unsigned u0 = gin[(size_t)c0.x * 20 + grel];
        unsigned u1 = gin[(size_t)c1.x * 20 + grel];
        unsigned u2 = gin[(size_t)c2.x * 20 + grel];
        unsigned u3 = gin[(size_t)c3.x * 20 + grel];
        float w0 = __int_as_float(c0.y), w1 = __int_as_float(c1.y);
        float w2 = __int_as_float(c2.y), w3 = __int_as_float(c3.y);
        aL0 = fmaf(w0, bfLo(u0), aL0); aH0 = fmaf(w0, bfHi(u0), aH0);
        aL1 = fmaf(w1, bfLo(u1), aL1); aH1 = fmaf(w1, bfHi(u1), aH1);
        aL2 = fmaf(w2, bfLo(u2), aL2); aH2 = fmaf(w2, bfHi(u2), aH2);
        aL3 = fmaf(w3, bfLo(u3), aL3); aH3 = fmaf(w3, bfHi(u3), aH3);
    }
    for (; j < e1; ++j) {
        int2 c = csr[j];
        unsigned u = gin[(size_t)c.x * 20 + grel];
        float w = __int_as_float(c.y);
        aL0 = fmaf(w, bfLo(u), aL0); aH0 = fmaf(w, bfHi(u), aH0);
    }
    if (act) {
        float dn = dis[node];
        float lo = dn * ((aL0 + aL1) + (aL2 + aL3));
        float hi = dn * ((aH0 + aH1) + (aH2 + aH3));
        gout[(size_t)node * 20 + grel] = (unsigned)f2bf(lo) | ((unsigned)f2bf(hi) << 16);
    }
}

// ---- conv2 + log_softmax epilogue; same 3-nodes/wave layout ----
__global__ __launch_bounds__(256) void spmv_final_kernel(
        const unsigned* __restrict__ g1, const unsigned* __restrict__ y,
        const float* __restrict__ bias, const int* __restrict__ start,
        const int2* __restrict__ csr, const float* __restrict__ dis,
        float* __restrict__ out, int N) {
    int lane = threadIdx.x & 63;
    int wid  = threadIdx.x >> 6;
    int grp  = lane / 20;
    int grel = lane - grp * 20;
    int node = blockIdx.x * 12 + wid * 3 + grp;
    bool act = (grp < 3) && (node < N);

    int e0 = 0, e1 = 0;
    if (act) { e0 = start[node]; e1 = start[node + 1]; }

    float aL0 = 0, aL1 = 0, aL2 = 0, aL3 = 0;
    float aH0 = 0, aH1 = 0, aH2 = 0, aH3 = 0;
    int j = e0;
    for (; j + 3 < e1; j += 4) {
        int2 c0 = csr[j], c1 = csr[j + 1], c2 = csr[j + 2], c3 = csr[j + 3];
        unsigned u0 = g1[(size_t)c0.x * 20 + grel];
        unsigned u1 = g1[(size_t)c1.x * 20 + grel];
        unsigned u2 = g1[(size_t)c2.x * 20 + grel];
        unsigned u3 = g1[(size_t)c3.x * 20 + grel];
        float w0 = __int_as_float(c0.y), w1 = __int_as_float(c1.y);
        float w2 = __int_as_float(c2.y), w3 = __int_as_float(c3.y);
        aL0 = fmaf(w0, bfLo(u0), aL0); aH0 = fmaf(w0, bfHi(u0), aH0);
        aL1 = fmaf(w1, bfLo(u1), aL1); aH1 = fmaf(w1, bfHi(u1), aH1);
        aL2 = fmaf(w2, bfLo(u2), aL2); aH2 = fmaf(w2, bfHi(u2), aH2);
        aL3 = fmaf(w3, bfLo(u3), aL3); aH3 = fmaf(w3, bfHi(u3), aH3);
    }
    for (; j < e1; ++j) {
        int2 c = csr[j];
        unsigned u = g1[(size_t)c.x * 20 + grel];
        float w = __int_as_float(c.y);
        aL0 = fmaf(w, bfLo(u), aL0); aH0 = fmaf(w, bfHi(u), aH0);
    }

    float logitL = 0.0f, logitH = 0.0f;
    if (act) {
        float dn  = dis[node];
        float g2L = dn * ((aL0 + aL1) + (aL2 + aL3));
        float g2H = dn * ((aH0 + aH1) + (aH2 + aH3));
        unsigned yu = y[(size_t)node * 20 + grel];
        unsigned gu = g1[(size_t)node * 20 + grel];
        float2 bv = *(const float2*)&bias[2 * grel];
        logitL = fmaf(ALPHA, bfLo(yu), fmaf(SCALE, bfLo(gu) + g2L, bv.x));
        logitH = fmaf(ALPHA, bfHi(yu), fmaf(SCALE, bfHi(gu) + g2H, bv.y));
    }

    // group (20-lane) reduce: max then sum, predicated shuffles
    float m = act ? fmaxf(logitL, logitH) : -INFINITY;
    #pragma unroll
    for (int off = 16; off; off >>= 1) {
        float o = __shfl(m, lane + off);
        if (grel + off < 20) m = fmaxf(m, o);
    }
    m = __shfl(m, grp * 20);   // broadcast group result

    float ex = act ? (expf(logitL - m) + expf(logitH - m)) : 0.0f;
    #pragma unroll
    for (int off = 16; off; off >>= 1) {
        float o = __shfl(ex, lane + off);
        if (grel + off < 20) ex += o;
    }
    ex = __shfl(ex, grp * 20);

    if (act) {
        float lse = m + logf(ex);
        float2 o;
        o.x = logitL - lse;
        o.y = logitH - lse;
        *(float2*)&out[(size_t)node * CDIM + 2 * grel] = o;
    }
}

extern "C" void kernel_launch(void* const* d_in, const int* in_sizes, int n_in,
                              void* d_out, int out_size, void* d_ws, size_t ws_size,
                              hipStream_t stream) {
    const float* x  = (const float*)d_in[0];   // [N,64]
    const float* ea = (const float*)d_in[1];   // [E]
    const float* W  = (const float*)d_in[2];   // [64,40]
    const float* b  = (const float*)d_in[3];   // [40]
    const int*   ei = (const int*)d_in[4];     // [2,E]: row then col

    const int N = in_sizes[0] / FDIM;
    const int E = in_sizes[1];
    const int* row = ei;
    const int* col = ei + E;
    const int NB = (N + 255) / 256;

    // workspace layout (4-byte units unless noted)
    int*   cnt   = (int*)d_ws;                     // NPAD
    int*   startp= cnt + NPAD;                     // NPAD (N+1 used)
    int*   bsums = startp + NPAD;                  // 1024
    float* dis   = (float*)(bsums + 1024);         // NPAD
    int2*  csr   = (int2*)(dis + NPAD);            // E int2
    unsigned* ybf  = (unsigned*)(csr + E);         // N*20 uints (bf16 y), aliased by slot
    unsigned* g1bf = ybf + (size_t)N * (CDIM / 2); // N*20 uints (bf16 g1)
    int*   slot  = (int*)ybf;                      // E ints, dead after fill

    hipMemsetAsync(cnt, 0, (size_t)NPAD * sizeof(int), stream);

    int histT = (E + 3) / 4;
    hist_kernel<<<(histT + 255) / 256, 256, 0, stream>>>(col, cnt, slot, E);
    scan_p1    <<<NB, 256, 0, stream>>>(cnt, startp, bsums, N);
    scan_p2    <<<1, 1024, 0, stream>>>(bsums, NB);
    scan_p3    <<<NB, 256, 0, stream>>>(startp, cnt, bsums, N, E);
    fill_kernel<<<2048, 256, 0, stream>>>(row, col, ea, slot, startp, csr, E);
    degdis_kernel<<<NB, 256, 0, stream>>>(startp, csr, dis, N);
    csr_scale_kernel<<<2048, 256, 0, stream>>>(csr, dis, E);
    lin_kernel <<<(N + 63) / 64, 256, 0, stream>>>(x, W, ybf, N);   // overwrites slot region

    int spmv_blocks = (N + 11) / 12;
    spmv_kernel      <<<spmv_blocks, 256, 0, stream>>>(ybf, startp, csr, dis, g1bf, N);
    spmv_final_kernel<<<spmv_blocks, 256, 0, stream>>>(g1bf, ybf, b, startp, csr, dis,
                                                       (float*)d_out, N);
}

// Round 8
// 204.531 us; speedup vs baseline: 4.1064x; 1.1272x over previous
//
#include <hip/hip_runtime.h>
#include <math.h>

// piSGC R8: atomic-free CSR build via 256-bucket MSD partition.
//  - part_hist: LDS histogram of col>>9 per block -> bin-major matrix H
//  - scan trio over H -> global scatter offsets; bb[k] = bucket bases
//  - part_scatter: partition (col,{row,ea}) into buckets, LDS offsets only
//  - bucket_csr: per-bucket (512 nodes) LDS count+scan -> start[] + final CSR
//  - spmv: 3 nodes/wave, 20 lanes/node, bf16x2 payload (unchanged from R7)

#define ALPHA  0.05f
#define SCALE  0.475f   // (1 - ALPHA) / NUM_LAYERS
#define FDIM   64
#define CDIM   40
#define NPAD   131072

__device__ __forceinline__ unsigned short f2bf(float f) {
    unsigned u = __float_as_uint(f);
    unsigned r = (u + 0x7FFFu + ((u >> 16) & 1u)) >> 16;   // round-nearest-even
    return (unsigned short)r;
}
__device__ __forceinline__ float bfLo(unsigned u) { return __uint_as_float(u << 16); }
__device__ __forceinline__ float bfHi(unsigned u) { return __uint_as_float(u & 0xffff0000u); }

// ---- partition histogram: H[bin*NBLK + blk] = #edges in blk's chunk with col>>9==bin ----
__global__ __launch_bounds__(256) void part_hist(const int* __restrict__ col,
                                                 int* __restrict__ H, int E, int NBLK) {
    __shared__ unsigned h[256];
    int tid = threadIdx.x, blk = blockIdx.x;
    h[tid] = 0;
    __syncthreads();
    #pragma unroll
    for (int i = 0; i < 8; ++i) {
        int e = blk * 2048 + i * 256 + tid;
        if (e < E) atomicAdd(&h[col[e] >> 9], 1u);
    }
    __syncthreads();
    H[tid * NBLK + blk] = h[tid];
}

// ---- scan pass 1: inclusive per-256-chunk scan of src -> dst, chunk sums ----
__global__ __launch_bounds__(256) void scan_p1(const int* __restrict__ src,
                                               int* __restrict__ dst,
                                               int* __restrict__ bsums, int M) {
    __shared__ int s[256];
    int tid = threadIdx.x;
    int i = blockIdx.x * 256 + tid;
    int v = (i < M) ? src[i] : 0;
    s[tid] = v;
    __syncthreads();
    for (int off = 1; off < 256; off <<= 1) {
        int t = (tid >= off) ? s[tid - off] : 0;
        __syncthreads();
        s[tid] += t;
        __syncthreads();
    }
    if (i < M) dst[i] = s[tid];
    if (tid == 255) bsums[blockIdx.x] = s[255];
}

// ---- scan pass 2: exclusive scan of chunk sums ----
__global__ __launch_bounds__(1024) void scan_p2(int* __restrict__ bsums, int NB) {
    __shared__ int s[1024];
    int tid = threadIdx.x;
    int carry = 0;
    for (int base = 0; base < NB; base += 1024) {
        int i = base + tid;
        int v = (i < NB) ? bsums[i] : 0;
        s[tid] = v;
        __syncthreads();
        for (int off = 1; off < 1024; off <<= 1) {
            int t = (tid >= off) ? s[tid - off] : 0;
            __syncthreads();
            s[tid] += t;
            __syncthreads();
        }
        if (i < NB) bsums[i] = carry + s[tid] - v;
        int tot = s[1023];
        __syncthreads();
        carry += tot;
    }
}

// ---- scan pass 3: dst[i] = inclusive + blockbase - src[i]  (exclusive global) ----
__global__ __launch_bounds__(256) void scan_p3(int* __restrict__ dst,
                                               const int* __restrict__ src,
                                               const int* __restrict__ bsums, int M) {
    int i = blockIdx.x * 256 + threadIdx.x;
    if (i < M) dst[i] += bsums[blockIdx.x] - src[i];
}

// ---- bucket bases: bb[k] = Hs[k*NBLK]; bb[256] = E ----
__global__ __launch_bounds__(256) void bb_extract(const int* __restrict__ Hs,
                                                  int* __restrict__ bb, int NBLK, int E) {
    int t = threadIdx.x;
    bb[t] = Hs[t * NBLK];
    if (t == 0) bb[256] = E;
}

// ---- partition scatter: pcol/ppay[p] for p in bucket regions ----
__global__ __launch_bounds__(256) void part_scatter(
        const int* __restrict__ row, const int* __restrict__ col,
        const float* __restrict__ ea, const int* __restrict__ Hs,
        int* __restrict__ pcol, int2* __restrict__ ppay, int E, int NBLK) {
    __shared__ unsigned offs[256];
    int tid = threadIdx.x, blk = blockIdx.x;
    offs[tid] = (unsigned)Hs[tid * NBLK + blk];
    __syncthreads();
    #pragma unroll
    for (int i = 0; i < 8; ++i) {
        int e = blk * 2048 + i * 256 + tid;
        if (e < E) {
            int c = col[e];
            unsigned p = atomicAdd(&offs[c >> 9], 1u);
            pcol[p] = c;
            ppay[p] = make_int2(row[e], __float_as_int(ea[e]));
        }
    }
}

// ---- per-bucket CSR finalize: start[] + csr[] (one block per bucket) ----
__global__ __launch_bounds__(256) void bucket_csr(
        const int* __restrict__ pcol, const int2* __restrict__ ppay,
        const int* __restrict__ bb, int* __restrict__ start,
        int2* __restrict__ csr, int N) {
    __shared__ unsigned cnt[512], exc[512], ofs[512], ps[256];
    int tid = threadIdx.x, k = blockIdx.x;
    int e0 = bb[k], e1 = bb[k + 1];

    cnt[tid] = 0; cnt[tid + 256] = 0;
    __syncthreads();
    for (int j = e0 + tid; j < e1; j += 256)
        atomicAdd(&cnt[pcol[j] & 511], 1u);
    __syncthreads();

    // exclusive scan of cnt[0..512)
    unsigned a0 = cnt[2 * tid], a1 = cnt[2 * tid + 1];
    unsigned pair = a0 + a1;
    ps[tid] = pair;
    __syncthreads();
    for (int off = 1; off < 256; off <<= 1) {
        unsigned t = (tid >= off) ? ps[tid - off] : 0;
        __syncthreads();
        ps[tid] += t;
        __syncthreads();
    }
    unsigned pexc = ps[tid] - pair;
    exc[2 * tid] = pexc;       exc[2 * tid + 1] = pexc + a0;
    ofs[2 * tid] = pexc;       ofs[2 * tid + 1] = pexc + a0;
    __syncthreads();

    // write start[] for this bucket's nodes (incl. node N -> E)
    #pragma unroll
    for (int i = tid; i < 512; i += 256) {
        int g = k * 512 + i;
        if (g <= N) start[g] = e0 + (int)exc[i];
    }

    // scatter payload into final CSR slots
    for (int j = e0 + tid; j < e1; j += 256) {
        int c = pcol[j];
        unsigned p = atomicAdd(&ofs[c & 511], 1u);
        csr[e0 + p] = ppay[j];
    }
}

// ---- deg+dis: segment sum of raw ea over CSR, then rsqrt ----
__global__ __launch_bounds__(256) void degdis_kernel(
        const int* __restrict__ start, const int2* __restrict__ csr,
        float* __restrict__ dis, int N) {
    int n = blockIdx.x * blockDim.x + threadIdx.x;
    if (n >= N) return;
    int e0 = start[n], e1 = start[n + 1];
    float d = 0.0f;
    for (int j = e0; j < e1; ++j) d += __int_as_float(csr[j].y);
    dis[n] = (d > 0.0f) ? rsqrtf(fmaxf(d, 1e-12f)) : 0.0f;
}

// ---- fold dis[src] into csr weight ----
__global__ void csr_scale_kernel(int2* __restrict__ csr,
                                 const float* __restrict__ dis, int E) {
    int stride = gridDim.x * blockDim.x;
    for (int e = blockIdx.x * blockDim.x + threadIdx.x; e < E; e += stride) {
        int2 a = csr[e];
        a.y = __float_as_int(__int_as_float(a.y) * dis[a.x]);
        csr[e] = a;
    }
}

// ---- y = x @ W, bf16 packed. 4 threads/node x 10 outputs, 64 nodes/block ----
__global__ __launch_bounds__(256) void lin_kernel(
        const float* __restrict__ x, const float* __restrict__ W,
        unsigned* __restrict__ ybf, int N) {
    __shared__ float sWt[CDIM][FDIM + 4];
    for (int i = threadIdx.x; i < FDIM * CDIM; i += 256) {
        int k = i / CDIM, c = i - k * CDIM;
        sWt[c][k] = W[i];
    }
    __syncthreads();

    int t = threadIdx.x;
    int node = blockIdx.x * 64 + (t >> 2);
    if (node >= N) return;
    int cs = (t & 3) * 10;

    float acc[10];
    #pragma unroll
    for (int i = 0; i < 10; ++i) acc[i] = 0.0f;

    const float4* xr = (const float4*)(x + (size_t)node * FDIM);
    #pragma unroll
    for (int k4 = 0; k4 < FDIM / 4; ++k4) {
        float4 v = xr[k4];
        #pragma unroll
        for (int i = 0; i < 10; ++i) {
            const float4 w = *(const float4*)&sWt[cs + i][k4 * 4];
            acc[i] = fmaf(v.x, w.x, fmaf(v.y, w.y, fmaf(v.z, w.z, fmaf(v.w, w.w, acc[i]))));
        }
    }

    unsigned* yr = ybf + (size_t)node * (CDIM / 2) + (t & 3) * 5;
    #pragma unroll
    for (int k = 0; k < 5; ++k)
        yr[k] = (unsigned)f2bf(acc[2 * k]) | ((unsigned)f2bf(acc[2 * k + 1]) << 16);
}

// ---- spmv1: g1[n] = dis[n] * sum_j w_j * y[src_j]; 3 nodes/wave, 20 lanes each ----
__global__ __launch_bounds__(256) void spmv_kernel(
        const unsigned* __restrict__ gin, const int* __restrict__ start,
        const int2* __restrict__ csr, const float* __restrict__ dis,
        unsigned* __restrict__ gout, int N) {
    int lane = threadIdx.x & 63;
    int wid  = threadIdx.x >> 6;
    int grp  = lane / 20;            // 0,1,2 active; 3 idle
    int grel = lane - grp * 20;
    int node = blockIdx.x * 12 + wid * 3 + grp;
    bool act = (grp < 3) && (node < N);

    int e0 = 0, e1 = 0;
    if (act) { e0 = start[node]; e1 = start[node + 1]; }

    float aL0 = 0, aL1 = 0, aL2 = 0, aL3 = 0;
    float aH0 = 0, aH1 = 0, aH2 = 0, aH3 = 0;
    int j = e0;
    for (; j + 3 < e1; j += 4) {
        int2 c0 = csr[j], c1 = csr[j + 1], c2 = csr[j + 2], c3 = csr[j + 3];
        unsigned u0 = gin[(size_t)c0.x * 20 + grel];
        unsigned u1 = gin[(size_t)c1.x * 20 + grel];
        unsigned u2 = gin[(size_t)c2.x * 20 + grel];
        unsigned u3 = gin[(size_t)c3.x * 20 + grel];
        float w0 = __int_as_float(c0.y), w1 = __int_as_float(c1.y);
        float w2 = __int_as_float(c2.y), w3 = __int_as_float(c3.y);
        aL0 = fmaf(w0, bfLo(u0), aL0); aH0 = fmaf(w0, bfHi(u0), aH0);
        aL1 = fmaf(w1, bfLo(u1), aL1); aH1 = fmaf(w1, bfHi(u1), aH1);
        aL2 = fmaf(w2, bfLo(u2), aL2); aH2 = fmaf(w2, bfHi(u2), aH2);
        aL3 = fmaf(w3, bfLo(u3), aL3); aH3 = fmaf(w3, bfHi(u3), aH3);
    }
    for (; j < e1; ++j) {
        int2 c = csr[j];
        unsigned u = gin[(size_t)c.x * 20 + grel];
        float w = __int_as_float(c.y);
        aL0 = fmaf(w, bfLo(u), aL0); aH0 = fmaf(w, bfHi(u), aH0);
    }
    if (act) {
        float dn = dis[node];
        float lo = dn * ((aL0 + aL1) + (aL2 + aL3));
        float hi = dn * ((aH0 + aH1) + (aH2 + aH3));
        gout[(size_t)node * 20 + grel] = (unsigned)f2bf(lo) | ((unsigned)f2bf(hi) << 16);
    }
}

// ---- conv2 + log_softmax epilogue; same 3-nodes/wave layout ----
__global__ __launch_bounds__(256) void spmv_final_kernel(
        const unsigned* __restrict__ g1, const unsigned* __restrict__ y,
        const float* __restrict__ bias, const int* __restrict__ start,
        const int2* __restrict__ csr, const float* __restrict__ dis,
        float* __restrict__ out, int N) {
    int lane = threadIdx.x & 63;
    int wid  = threadIdx.x >> 6;
    int grp  = lane / 20;
    int grel = lane - grp * 20;
    int node = blockIdx.x * 12 + wid * 3 + grp;
    bool act = (grp < 3) && (node < N);

    int e0 = 0, e1 = 0;
    if (act) { e0 = start[node]; e1 = start[node + 1]; }

    float aL0 = 0, aL1 = 0, aL2 = 0, aL3 = 0;
    float aH0 = 0, aH1 = 0, aH2 = 0, aH3 = 0;
    int j = e0;
    for (; j + 3 < e1; j += 4) {
        int2 c0 = csr[j], c1 = csr[j + 1], c2 = csr[j + 2], c3 = csr[j + 3];
        unsigned u0 = g1[(size_t)c0.x * 20 + grel];
        unsigned u1 = g1[(size_t)c1.x * 20 + grel];
        unsigned u2 = g1[(size_t)c2.x * 20 + grel];
        unsigned u3 = g1[(size_t)c3.x * 20 + grel];
        float w0 = __int_as_float(c0.y), w1 = __int_as_float(c1.y);
        float w2 = __int_as_float(c2.y), w3 = __int_as_float(c3.y);
        aL0 = fmaf(w0, bfLo(u0), aL0); aH0 = fmaf(w0, bfHi(u0), aH0);
        aL1 = fmaf(w1, bfLo(u1), aL1); aH1 = fmaf(w1, bfHi(u1), aH1);
        aL2 = fmaf(w2, bfLo(u2), aL2); aH2 = fmaf(w2, bfHi(u2), aH2);
        aL3 = fmaf(w3, bfLo(u3), aL3); aH3 = fmaf(w3, bfHi(u3), aH3);
    }
    for (; j < e1; ++j) {
        int2 c = csr[j];
        unsigned u = g1[(size_t)c.x * 20 + grel];
        float w = __int_as_float(c.y);
        aL0 = fmaf(w, bfLo(u), aL0); aH0 = fmaf(w, bfHi(u), aH0);
    }

    float logitL = 0.0f, logitH = 0.0f;
    if (act) {
        float dn  = dis[node];
        float g2L = dn * ((aL0 + aL1) + (aL2 + aL3));
        float g2H = dn * ((aH0 + aH1) + (aH2 + aH3));
        unsigned yu = y[(size_t)node * 20 + grel];
        unsigned gu = g1[(size_t)node * 20 + grel];
        float2 bv = *(const float2*)&bias[2 * grel];
        logitL = fmaf(ALPHA, bfLo(yu), fmaf(SCALE, bfLo(gu) + g2L, bv.x));
        logitH = fmaf(ALPHA, bfHi(yu), fmaf(SCALE, bfHi(gu) + g2H, bv.y));
    }

    float m = act ? fmaxf(logitL, logitH) : -INFINITY;
    #pragma unroll
    for (int off = 16; off; off >>= 1) {
        float o = __shfl(m, lane + off);
        if (grel + off < 20) m = fmaxf(m, o);
    }
    m = __shfl(m, grp * 20);

    float ex = act ? (expf(logitL - m) + expf(logitH - m)) : 0.0f;
    #pragma unroll
    for (int off = 16; off; off >>= 1) {
        float o = __shfl(ex, lane + off);
        if (grel + off < 20) ex += o;
    }
    ex = __shfl(ex, grp * 20);

    if (act) {
        float lse = m + logf(ex);
        float2 o;
        o.x = logitL - lse;
        o.y = logitH - lse;
        *(float2*)&out[(size_t)node * CDIM + 2 * grel] = o;
    }
}

extern "C" void kernel_launch(void* const* d_in, const int* in_sizes, int n_in,
                              void* d_out, int out_size, void* d_ws, size_t ws_size,
                              hipStream_t stream) {
    const float* x  = (const float*)d_in[0];   // [N,64]
    const float* ea = (const float*)d_in[1];   // [E]
    const float* W  = (const float*)d_in[2];   // [64,40]
    const float* b  = (const float*)d_in[3];   // [40]
    const int*   ei = (const int*)d_in[4];     // [2,E]: row then col

    const int N = in_sizes[0] / FDIM;
    const int E = in_sizes[1];
    const int* row = ei;
    const int* col = ei + E;

    const int NBLK = (E + 2047) / 2048;        // partition blocks
    const int M    = 256 * NBLK;               // hist matrix size

    // workspace layout (4-byte words; all regions fully overwritten each call)
    int*   startp = (int*)d_ws;                  // NPAD
    float* dis    = (float*)(startp + NPAD);     // NPAD
    int*   bb     = (int*)(dis + NPAD);          // 1024 (257 used)
    int*   bsums  = bb + 1024;                   // 1024
    int*   H      = bsums + 1024;                // M
    int*   Hs     = H + M;                       // M
    int*   pcol   = Hs + M;                      // E
    int2*  ppay   = (int2*)(pcol + E);           // E int2
    int2*  csr    = ppay + E;                    // E int2
    unsigned* g1bf = (unsigned*)(csr + E);       // N*20
    unsigned* ybf  = (unsigned*)ppay;            // aliases ppay (dead after bucket_csr)

    part_hist   <<<NBLK, 256, 0, stream>>>(col, H, E, NBLK);
    scan_p1     <<<M / 256, 256, 0, stream>>>(H, Hs, bsums, M);
    scan_p2     <<<1, 1024, 0, stream>>>(bsums, M / 256);
    scan_p3     <<<M / 256, 256, 0, stream>>>(Hs, H, bsums, M);
    bb_extract  <<<1, 256, 0, stream>>>(Hs, bb, NBLK, E);
    part_scatter<<<NBLK, 256, 0, stream>>>(row, col, ea, Hs, pcol, ppay, E, NBLK);
    bucket_csr  <<<256, 256, 0, stream>>>(pcol, ppay, bb, startp, csr, N);
    degdis_kernel<<<(N + 255) / 256, 256, 0, stream>>>(startp, csr, dis, N);
    csr_scale_kernel<<<2048, 256, 0, stream>>>(csr, dis, E);
    lin_kernel  <<<(N + 63) / 64, 256, 0, stream>>>(x, W, ybf, N);

    int spmv_blocks = (N + 11) / 12;
    spmv_kernel      <<<spmv_blocks, 256, 0, stream>>>(ybf, startp, csr, dis, g1bf, N);
    spmv_final_kernel<<<spmv_blocks, 256, 0, stream>>>(g1bf, ybf, b, startp, csr, dis,
                                                       (float*)d_out, N);
}

// Round 9
// 175.568 us; speedup vs baseline: 4.7838x; 1.1650x over previous
//
#include <hip/hip_runtime.h>
#include <math.h>

// piSGC R9: atomic-free CSR build, packed 8B partition payload.
//  - ppay.x = row | ((col&511)<<20): single scattered array in part_scatter
//  - bucket_csr also accumulates deg in LDS -> writes dis (degdis kernel gone)
//  - spmv: 3 nodes/wave, 20 lanes/node, 8-deep unrolled gathers

#define ALPHA  0.05f
#define SCALE  0.475f   // (1 - ALPHA) / NUM_LAYERS
#define FDIM   64
#define CDIM   40
#define NPAD   131072

__device__ __forceinline__ unsigned short f2bf(float f) {
    unsigned u = __float_as_uint(f);
    unsigned r = (u + 0x7FFFu + ((u >> 16) & 1u)) >> 16;   // round-nearest-even
    return (unsigned short)r;
}
__device__ __forceinline__ float bfLo(unsigned u) { return __uint_as_float(u << 16); }
__device__ __forceinline__ float bfHi(unsigned u) { return __uint_as_float(u & 0xffff0000u); }

// ---- partition histogram: H[bin*NBLK + blk] ----
__global__ __launch_bounds__(256) void part_hist(const int* __restrict__ col,
                                                 int* __restrict__ H, int E, int NBLK) {
    __shared__ unsigned h[256];
    int tid = threadIdx.x, blk = blockIdx.x;
    h[tid] = 0;
    __syncthreads();
    #pragma unroll
    for (int i = 0; i < 8; ++i) {
        int e = blk * 2048 + i * 256 + tid;
        if (e < E) atomicAdd(&h[col[e] >> 9], 1u);
    }
    __syncthreads();
    H[tid * NBLK + blk] = h[tid];
}

// ---- scan pass 1 ----
__global__ __launch_bounds__(256) void scan_p1(const int* __restrict__ src,
                                               int* __restrict__ dst,
                                               int* __restrict__ bsums, int M) {
    __shared__ int s[256];
    int tid = threadIdx.x;
    int i = blockIdx.x * 256 + tid;
    int v = (i < M) ? src[i] : 0;
    s[tid] = v;
    __syncthreads();
    for (int off = 1; off < 256; off <<= 1) {
        int t = (tid >= off) ? s[tid - off] : 0;
        __syncthreads();
        s[tid] += t;
        __syncthreads();
    }
    if (i < M) dst[i] = s[tid];
    if (tid == 255) bsums[blockIdx.x] = s[255];
}

// ---- scan pass 2 ----
__global__ __launch_bounds__(1024) void scan_p2(int* __restrict__ bsums, int NB) {
    __shared__ int s[1024];
    int tid = threadIdx.x;
    int carry = 0;
    for (int base = 0; base < NB; base += 1024) {
        int i = base + tid;
        int v = (i < NB) ? bsums[i] : 0;
        s[tid] = v;
        __syncthreads();
        for (int off = 1; off < 1024; off <<= 1) {
            int t = (tid >= off) ? s[tid - off] : 0;
            __syncthreads();
            s[tid] += t;
            __syncthreads();
        }
        if (i < NB) bsums[i] = carry + s[tid] - v;
        int tot = s[1023];
        __syncthreads();
        carry += tot;
    }
}

// ---- scan pass 3 ----
__global__ __launch_bounds__(256) void scan_p3(int* __restrict__ dst,
                                               const int* __restrict__ src,
                                               const int* __restrict__ bsums, int M) {
    int i = blockIdx.x * 256 + threadIdx.x;
    if (i < M) dst[i] += bsums[blockIdx.x] - src[i];
}

// ---- bucket bases ----
__global__ __launch_bounds__(256) void bb_extract(const int* __restrict__ Hs,
                                                  int* __restrict__ bb, int NBLK, int E) {
    int t = threadIdx.x;
    bb[t] = Hs[t * NBLK];
    if (t == 0) bb[256] = E;
}

// ---- partition scatter: single packed int2 array ----
__global__ __launch_bounds__(256) void part_scatter(
        const int* __restrict__ row, const int* __restrict__ col,
        const float* __restrict__ ea, const int* __restrict__ Hs,
        int2* __restrict__ ppay, int E, int NBLK) {
    __shared__ unsigned offs[256];
    int tid = threadIdx.x, blk = blockIdx.x;
    offs[tid] = (unsigned)Hs[tid * NBLK + blk];
    __syncthreads();
    #pragma unroll
    for (int i = 0; i < 8; ++i) {
        int e = blk * 2048 + i * 256 + tid;
        if (e < E) {
            int c = col[e];
            unsigned p = atomicAdd(&offs[c >> 9], 1u);
            ppay[p] = make_int2(row[e] | ((c & 511) << 20), __float_as_int(ea[e]));
        }
    }
}

// ---- per-bucket CSR finalize + deg/dis (one block per bucket) ----
__global__ __launch_bounds__(256) void bucket_csr(
        const int2* __restrict__ ppay, const int* __restrict__ bb,
        int* __restrict__ start, int2* __restrict__ csr,
        float* __restrict__ dis, int N) {
    __shared__ unsigned cnt[512], exc[512], ofs[512], ps[256];
    __shared__ float sdeg[512];
    int tid = threadIdx.x, k = blockIdx.x;
    int e0 = bb[k], e1 = bb[k + 1];

    cnt[tid] = 0; cnt[tid + 256] = 0;
    sdeg[tid] = 0.0f; sdeg[tid + 256] = 0.0f;
    __syncthreads();
    for (int j = e0 + tid; j < e1; j += 256) {
        int2 pay = ppay[j];
        int c = (pay.x >> 20) & 511;
        atomicAdd(&cnt[c], 1u);
        atomicAdd(&sdeg[c], __int_as_float(pay.y));
    }
    __syncthreads();

    // exclusive scan of cnt[0..512)
    unsigned a0 = cnt[2 * tid], a1 = cnt[2 * tid + 1];
    unsigned pair = a0 + a1;
    ps[tid] = pair;
    __syncthreads();
    for (int off = 1; off < 256; off <<= 1) {
        unsigned t = (tid >= off) ? ps[tid - off] : 0;
        __syncthreads();
        ps[tid] += t;
        __syncthreads();
    }
    unsigned pexc = ps[tid] - pair;
    exc[2 * tid] = pexc;       exc[2 * tid + 1] = pexc + a0;
    ofs[2 * tid] = pexc;       ofs[2 * tid + 1] = pexc + a0;
    __syncthreads();

    // start[] and dis[] for this bucket's nodes
    #pragma unroll
    for (int i = tid; i < 512; i += 256) {
        int g = k * 512 + i;
        if (g <= N) start[g] = e0 + (int)exc[i];
        if (g < N) {
            float d = sdeg[i];
            dis[g] = (d > 0.0f) ? rsqrtf(fmaxf(d, 1e-12f)) : 0.0f;
        }
    }

    // scatter payload into final CSR slots (strip col bits)
    for (int j = e0 + tid; j < e1; j += 256) {
        int2 pay = ppay[j];
        int c = (pay.x >> 20) & 511;
        unsigned p = atomicAdd(&ofs[c], 1u);
        csr[e0 + p] = make_int2(pay.x & 0xFFFFF, pay.y);
    }
}

// ---- fold dis[src] into csr weight ----
__global__ void csr_scale_kernel(int2* __restrict__ csr,
                                 const float* __restrict__ dis, int E) {
    int stride = gridDim.x * blockDim.x;
    for (int e = blockIdx.x * blockDim.x + threadIdx.x; e < E; e += stride) {
        int2 a = csr[e];
        a.y = __float_as_int(__int_as_float(a.y) * dis[a.x]);
        csr[e] = a;
    }
}

// ---- y = x @ W, bf16 packed. 4 threads/node x 10 outputs ----
__global__ __launch_bounds__(256) void lin_kernel(
        const float* __restrict__ x, const float* __restrict__ W,
        unsigned* __restrict__ ybf, int N) {
    __shared__ float sWt[CDIM][FDIM + 4];
    for (int i = threadIdx.x; i < FDIM * CDIM; i += 256) {
        int k = i / CDIM, c = i - k * CDIM;
        sWt[c][k] = W[i];
    }
    __syncthreads();

    int t = threadIdx.x;
    int node = blockIdx.x * 64 + (t >> 2);
    if (node >= N) return;
    int cs = (t & 3) * 10;

    float acc[10];
    #pragma unroll
    for (int i = 0; i < 10; ++i) acc[i] = 0.0f;

    const float4* xr = (const float4*)(x + (size_t)node * FDIM);
    #pragma unroll
    for (int k4 = 0; k4 < FDIM / 4; ++k4) {
        float4 v = xr[k4];
        #pragma unroll
        for (int i = 0; i < 10; ++i) {
            const float4 w = *(const float4*)&sWt[cs + i][k4 * 4];
            acc[i] = fmaf(v.x, w.x, fmaf(v.y, w.y, fmaf(v.z, w.z, fmaf(v.w, w.w, acc[i]))));
        }
    }

    unsigned* yr = ybf + (size_t)node * (CDIM / 2) + (t & 3) * 5;
    #pragma unroll
    for (int k = 0; k < 5; ++k)
        yr[k] = (unsigned)f2bf(acc[2 * k]) | ((unsigned)f2bf(acc[2 * k + 1]) << 16);
}

// ---- spmv1: 3 nodes/wave, 20 lanes each, 8-deep unroll ----
__global__ __launch_bounds__(256) void spmv_kernel(
        const unsigned* __restrict__ gin, const int* __restrict__ start,
        const int2* __restrict__ csr, const float* __restrict__ dis,
        unsigned* __restrict__ gout, int N) {
    int lane = threadIdx.x & 63;
    int wid  = threadIdx.x >> 6;
    int grp  = lane / 20;
    int grel = lane - grp * 20;
    int node = blockIdx.x * 12 + wid * 3 + grp;
    bool act = (grp < 3) && (node < N);

    int e0 = 0, e1 = 0;
    if (act) { e0 = start[node]; e1 = start[node + 1]; }

    float aL0 = 0, aL1 = 0, aL2 = 0, aL3 = 0;
    float aH0 = 0, aH1 = 0, aH2 = 0, aH3 = 0;
    int j = e0;
    for (; j + 7 < e1; j += 8) {
        int2 c0 = csr[j],     c1 = csr[j + 1], c2 = csr[j + 2], c3 = csr[j + 3];
        int2 c4 = csr[j + 4], c5 = csr[j + 5], c6 = csr[j + 6], c7 = csr[j + 7];
        unsigned u0 = gin[(size_t)c0.x * 20 + grel];
        unsigned u1 = gin[(size_t)c1.x * 20 + grel];
        unsigned u2 = gin[(size_t)c2.x * 20 + grel];
        unsigned u3 = gin[(size_t)c3.x * 20 + grel];
        unsigned u4 = gin[(size_t)c4.x * 20 + grel];
        unsigned u5 = gin[(size_t)c5.x * 20 + grel];
        unsigned u6 = gin[(size_t)c6.x * 20 + grel];
        unsigned u7 = gin[(size_t)c7.x * 20 + grel];
        float w0 = __int_as_float(c0.y), w1 = __int_as_float(c1.y);
        float w2 = __int_as_float(c2.y), w3 = __int_as_float(c3.y);
        float w4 = __int_as_float(c4.y), w5 = __int_as_float(c5.y);
        float w6 = __int_as_float(c6.y), w7 = __int_as_float(c7.y);
        aL0 = fmaf(w0, bfLo(u0), aL0); aH0 = fmaf(w0, bfHi(u0), aH0);
        aL1 = fmaf(w1, bfLo(u1), aL1); aH1 = fmaf(w1, bfHi(u1), aH1);
        aL2 = fmaf(w2, bfLo(u2), aL2); aH2 = fmaf(w2, bfHi(u2), aH2);
        aL3 = fmaf(w3, bfLo(u3), aL3); aH3 = fmaf(w3, bfHi(u3), aH3);
        aL0 = fmaf(w4, bfLo(u4), aL0); aH0 = fmaf(w4, bfHi(u4), aH0);
        aL1 = fmaf(w5, bfLo(u5), aL1); aH1 = fmaf(w5, bfHi(u5), aH1);
        aL2 = fmaf(w6, bfLo(u6), aL2); aH2 = fmaf(w6, bfHi(u6), aH2);
        aL3 = fmaf(w7, bfLo(u7), aL3); aH3 = fmaf(w7, bfHi(u7), aH3);
    }
    for (; j < e1; ++j) {
        int2 c = csr[j];
        unsigned u = gin[(size_t)c.x * 20 + grel];
        float w = __int_as_float(c.y);
        aL0 = fmaf(w, bfLo(u), aL0); aH0 = fmaf(w, bfHi(u), aH0);
    }
    if (act) {
        float dn = dis[node];
        float lo = dn * ((aL0 + aL1) + (aL2 + aL3));
        float hi = dn * ((aH0 + aH1) + (aH2 + aH3));
        gout[(size_t)node * 20 + grel] = (unsigned)f2bf(lo) | ((unsigned)f2bf(hi) << 16);
    }
}

// ---- conv2 + log_softmax epilogue ----
__global__ __launch_bounds__(256) void spmv_final_kernel(
        const unsigned* __restrict__ g1, const unsigned* __restrict__ y,
        const float* __restrict__ bias, const int* __restrict__ start,
        const int2* __restrict__ csr, const float* __restrict__ dis,
        float* __restrict__ out, int N) {
    int lane = threadIdx.x & 63;
    int wid  = threadIdx.x >> 6;
    int grp  = lane / 20;
    int grel = lane - grp * 20;
    int node = blockIdx.x * 12 + wid * 3 + grp;
    bool act = (grp < 3) && (node < N);

    int e0 = 0, e1 = 0;
    if (act) { e0 = start[node]; e1 = start[node + 1]; }

    float aL0 = 0, aL1 = 0, aL2 = 0, aL3 = 0;
    float aH0 = 0, aH1 = 0, aH2 = 0, aH3 = 0;
    int j = e0;
    for (; j + 7 < e1; j += 8) {
        int2 c0 = csr[j],     c1 = csr[j + 1], c2 = csr[j + 2], c3 = csr[j + 3];
        int2 c4 = csr[j + 4], c5 = csr[j + 5], c6 = csr[j + 6], c7 = csr[j + 7];
        unsigned u0 = g1[(size_t)c0.x * 20 + grel];
        unsigned u1 = g1[(size_t)c1.x * 20 + grel];
        unsigned u2 = g1[(size_t)c2.x * 20 + grel];
        unsigned u3 = g1[(size_t)c3.x * 20 + grel];
        unsigned u4 = g1[(size_t)c4.x * 20 + grel];
        unsigned u5 = g1[(size_t)c5.x * 20 + grel];
        unsigned u6 = g1[(size_t)c6.x * 20 + grel];
        unsigned u7 = g1[(size_t)c7.x * 20 + grel];
        float w0 = __int_as_float(c0.y), w1 = __int_as_float(c1.y);
        float w2 = __int_as_float(c2.y), w3 = __int_as_float(c3.y);
        float w4 = __int_as_float(c4.y), w5 = __int_as_float(c5.y);
        float w6 = __int_as_float(c6.y), w7 = __int_as_float(c7.y);
        aL0 = fmaf(w0, bfLo(u0), aL0); aH0 = fmaf(w0, bfHi(u0), aH0);
        aL1 = fmaf(w1, bfLo(u1), aL1); aH1 = fmaf(w1, bfHi(u1), aH1);
        aL2 = fmaf(w2, bfLo(u2), aL2); aH2 = fmaf(w2, bfHi(u2), aH2);
        aL3 = fmaf(w3, bfLo(u3), aL3); aH3 = fmaf(w3, bfHi(u3), aH3);
        aL0 = fmaf(w4, bfLo(u4), aL0); aH0 = fmaf(w4, bfHi(u4), aH0);
        aL1 = fmaf(w5, bfLo(u5), aL1); aH1 = fmaf(w5, bfHi(u5), aH1);
        aL2 = fmaf(w6, bfLo(u6), aL2); aH2 = fmaf(w6, bfHi(u6), aH2);
        aL3 = fmaf(w7, bfLo(u7), aL3); aH3 = fmaf(w7, bfHi(u7), aH3);
    }
    for (; j < e1; ++j) {
        int2 c = csr[j];
        unsigned u = g1[(size_t)c.x * 20 + grel];
        float w = __int_as_float(c.y);
        aL0 = fmaf(w, bfLo(u), aL0); aH0 = fmaf(w, bfHi(u), aH0);
    }

    float logitL = 0.0f, logitH = 0.0f;
    if (act) {
        float dn  = dis[node];
        float g2L = dn * ((aL0 + aL1) + (aL2 + aL3));
        float g2H = dn * ((aH0 + aH1) + (aH2 + aH3));
        unsigned yu = y[(size_t)node * 20 + grel];
        unsigned gu = g1[(size_t)node * 20 + grel];
        float2 bv = *(const float2*)&bias[2 * grel];
        logitL = fmaf(ALPHA, bfLo(yu), fmaf(SCALE, bfLo(gu) + g2L, bv.x));
        logitH = fmaf(ALPHA, bfHi(yu), fmaf(SCALE, bfHi(gu) + g2H, bv.y));
    }

    float m = act ? fmaxf(logitL, logitH) : -INFINITY;
    #pragma unroll
    for (int off = 16; off; off >>= 1) {
        float o = __shfl(m, lane + off);
        if (grel + off < 20) m = fmaxf(m, o);
    }
    m = __shfl(m, grp * 20);

    float ex = act ? (expf(logitL - m) + expf(logitH - m)) : 0.0f;
    #pragma unroll
    for (int off = 16; off; off >>= 1) {
        float o = __shfl(ex, lane + off);
        if (grel + off < 20) ex += o;
    }
    ex = __shfl(ex, grp * 20);

    if (act) {
        float lse = m + logf(ex);
        float2 o;
        o.x = logitL - lse;
        o.y = logitH - lse;
        *(float2*)&out[(size_t)node * CDIM + 2 * grel] = o;
    }
}

extern "C" void kernel_launch(void* const* d_in, const int* in_sizes, int n_in,
                              void* d_out, int out_size, void* d_ws, size_t ws_size,
                              hipStream_t stream) {
    const float* x  = (const float*)d_in[0];   // [N,64]
    const float* ea = (const float*)d_in[1];   // [E]
    const float* W  = (const float*)d_in[2];   // [64,40]
    const float* b  = (const float*)d_in[3];   // [40]
    const int*   ei = (const int*)d_in[4];     // [2,E]: row then col

    const int N = in_sizes[0] / FDIM;
    const int E = in_sizes[1];
    const int* row = ei;
    const int* col = ei + E;

    const int NBLK = (E + 2047) / 2048;        // partition blocks
    const int M    = 256 * NBLK;               // hist matrix size (multiple of 256)

    // workspace layout (4-byte words; all regions fully overwritten each call)
    int*   startp = (int*)d_ws;                  // NPAD
    float* dis    = (float*)(startp + NPAD);     // NPAD
    int*   bb     = (int*)(dis + NPAD);          // 1024 (257 used)
    int*   bsums  = bb + 1024;                   // 1024
    int*   H      = bsums + 1024;                // M
    int*   Hs     = H + M;                       // M
    int2*  ppay   = (int2*)(Hs + M);             // E int2
    int2*  csr    = ppay + E;                    // E int2
    unsigned* g1bf = (unsigned*)(csr + E);       // N*20
    unsigned* ybf  = (unsigned*)ppay;            // aliases ppay (dead after bucket_csr)

    part_hist   <<<NBLK, 256, 0, stream>>>(col, H, E, NBLK);
    scan_p1     <<<M / 256, 256, 0, stream>>>(H, Hs, bsums, M);
    scan_p2     <<<1, 1024, 0, stream>>>(bsums, M / 256);
    scan_p3     <<<M / 256, 256, 0, stream>>>(Hs, H, bsums, M);
    bb_extract  <<<1, 256, 0, stream>>>(Hs, bb, NBLK, E);
    part_scatter<<<NBLK, 256, 0, stream>>>(row, col, ea, Hs, ppay, E, NBLK);
    bucket_csr  <<<256, 256, 0, stream>>>(ppay, bb, startp, csr, dis, N);
    csr_scale_kernel<<<2048, 256, 0, stream>>>(csr, dis, E);
    lin_kernel  <<<(N + 63) / 64, 256, 0, stream>>>(x, W, ybf, N);

    int spmv_blocks = (N + 11) / 12;
    spmv_kernel      <<<spmv_blocks, 256, 0, stream>>>(ybf, startp, csr, dis, g1bf, N);
    spmv_final_kernel<<<spmv_blocks, 256, 0, stream>>>(g1bf, ybf, b, startp, csr, dis,
                                                       (float*)d_out, N);
}